// Round 11
// baseline (1841.953 us; speedup 1.0000x reference)
//
#include <hip/hip_runtime.h>
#include <math.h>

#define NLEN 12096
#define BB 2

typedef __bf16 bhalf;
typedef bhalf bh8 __attribute__((ext_vector_type(8)));
typedef bhalf bh4 __attribute__((ext_vector_type(4)));
typedef float f32x4 __attribute__((ext_vector_type(4)));

// BK=64 LDS swizzle: 8 16B-slots per 128B row; physical slot p holds logical
// unit p ^ (row&7). Per 32-lane read half-pass: 4 lanes/slot -> 4-cycle
// minimum, conflict-free (same balance argument verified at BK=32, round 8).
__device__ __forceinline__ int swz8(int row) { return row & 7; }

// Bijective XCD-chunk swizzle (T1, m204).
__device__ __forceinline__ int xcd_swz(int id, int nwg) {
  int q = nwg >> 3, r = nwg & 7;
  int xcd = id & 7, pos = id >> 3;
  int base = (xcd < r) ? xcd * (q + 1) : r * (q + 1) + (xcd - r) * q;
  return base + pos;
}

#define GLOAD_LDS16(g, l) \
  __builtin_amdgcn_global_load_lds( \
      (const __attribute__((address_space(1))) unsigned int*)(g), \
      (__attribute__((address_space(3))) unsigned int*)(l), 16, 0, 0)

// =====================================================================
// bf16 MFMA GEMM: C[M,N] = A[M,K] @ Bt[N,K]^T  (+bias[n]) (+relu)
// Tile 128x128, BK=64 (2 MFMA k-slices per barrier pair), gload_lds.
// =====================================================================
__global__ __launch_bounds__(256) void bgemm_kernel(
    const bhalf* __restrict__ A, const bhalf* __restrict__ Bt,
    const float* __restrict__ bias, void* __restrict__ Cout,
    int M, int N, int K, long long sA, long long sB, long long sC,
    int outBf16, int relu)
{
  const int gx = gridDim.x, gy = gridDim.y;
  const int nwg = gx * gy * gridDim.z;
  int flat = (blockIdx.z * gy + blockIdx.y) * gx + blockIdx.x;
  int logical = xcd_swz(flat, nwg);
  const int bz = logical / (gx * gy);
  int rem = logical - bz * gx * gy;
  const int by = rem / gx;
  const int bx = rem - by * gx;

  A += bz * sA; Bt += bz * sB;
  const int m0 = by * 128, n0 = bx * 128;
  __shared__ __align__(16) bhalf As[128 * 64];
  __shared__ __align__(16) bhalf Bs[128 * 64];
  const int t = threadIdx.x;
  const int lane = t & 63;
  const int w = t >> 6;
  const int wbase = t & 192;
  const int wm = (w >> 1) * 64, wn = (w & 1) * 64;
  const int fr = lane & 15, fg = lane >> 4;
  f32x4 acc[4][4] = {};
  for (int k0 = 0; k0 < K; k0 += 64) {
#pragma unroll
    for (int j = 0; j < 4; ++j) {
      int id = t + j * 256;
      int row = id >> 3, up = id & 7;
      int kcg = ((up ^ swz8(row)) * 8);
      int m = m0 + row; m = (m < M) ? m : (M - 1);
      GLOAD_LDS16(A + (long long)m * K + k0 + kcg, As + (wbase + j * 256) * 8);
      int n = n0 + row; n = (n < N) ? n : (N - 1);
      GLOAD_LDS16(Bt + (long long)n * K + k0 + kcg, Bs + (wbase + j * 256) * 8);
    }
    __syncthreads();
#pragma unroll
    for (int kk = 0; kk < 2; ++kk) {
      bh8 af[4], bf[4];
      const int ub = kk * 4 + fg;
#pragma unroll
      for (int mi = 0; mi < 4; ++mi) {
        int r = wm + mi * 16 + fr;
        af[mi] = *(const bh8*)(As + r * 64 + ((ub ^ swz8(r)) * 8));
      }
#pragma unroll
      for (int ni = 0; ni < 4; ++ni) {
        int r = wn + ni * 16 + fr;
        bf[ni] = *(const bh8*)(Bs + r * 64 + ((ub ^ swz8(r)) * 8));
      }
#pragma unroll
      for (int mi = 0; mi < 4; ++mi)
#pragma unroll
        for (int ni = 0; ni < 4; ++ni)
          acc[mi][ni] = __builtin_amdgcn_mfma_f32_16x16x32_bf16(af[mi], bf[ni], acc[mi][ni], 0, 0, 0);
    }
    __syncthreads();
  }
  float* Cf = (float*)Cout + bz * sC;
  bhalf* Cb = (bhalf*)Cout + bz * sC;
#pragma unroll
  for (int mi = 0; mi < 4; ++mi) {
#pragma unroll
    for (int r = 0; r < 4; ++r) {
      int m = m0 + wm + mi * 16 + fg * 4 + r;
      if (m >= M) continue;
#pragma unroll
      for (int ni = 0; ni < 4; ++ni) {
        int n = n0 + wn + ni * 16 + fr;
        if (n >= N) continue;
        float v = acc[mi][ni][r];
        if (bias) v += bias[n];
        if (relu) v = fmaxf(v, 0.f);
        if (outBf16) Cb[(long long)m * N + n] = (bhalf)v;
        else         Cf[(long long)m * N + n] = v;
      }
    }
  }
}

// =====================================================================
// Fused GEMM + bias + residual + LayerNorm. Tile 64x256, BK=64.
// y = LN(src + A@Bt^T + bias); writes src fp32, srcb bf16, qb = y+pos.
// M divisible by 64; N fixed 256.
// =====================================================================
__global__ __launch_bounds__(256) void bgemm_ln_kernel(
    const bhalf* __restrict__ A, const bhalf* __restrict__ Bt,
    const float* __restrict__ bias,
    float* __restrict__ src, bhalf* __restrict__ srcb,
    bhalf* __restrict__ qbOut, const float* __restrict__ pos,
    const float* __restrict__ ls, const float* __restrict__ lb,
    int M, int K)
{
  const int nwg = gridDim.x;
  const int bid = xcd_swz(blockIdx.x, nwg);
  const int m0 = bid * 64;
  // rows 0..63 = A-tile, rows 64..319 = Bt (all 256 weight rows); 40 KB
  __shared__ __align__(16) bhalf Ls[320 * 64];
  bhalf* AsL = Ls;
  bhalf* BsL = Ls + 64 * 64;
  __shared__ float shS[64][2], shQ[64][2];
  const int t = threadIdx.x;
  const int lane = t & 63;
  const int w = t >> 6;
  const int wbase = t & 192;
  const int wm = (w >> 1) * 32, wn = (w & 1) * 128;
  const int fr = lane & 15, fg = lane >> 4;
  f32x4 acc[2][8] = {};
  for (int k0 = 0; k0 < K; k0 += 64) {
#pragma unroll
    for (int j = 0; j < 10; ++j) {
      int id = t + j * 256;
      int row = id >> 3, up = id & 7;
      int kcg = ((up ^ swz8(row)) * 8);
      const bhalf* gsrc = (row < 64)
          ? (A + (long long)(m0 + row) * K + k0 + kcg)
          : (Bt + (long long)(row - 64) * K + k0 + kcg);
      GLOAD_LDS16(gsrc, Ls + (wbase + j * 256) * 8);
    }
    __syncthreads();
#pragma unroll
    for (int kk = 0; kk < 2; ++kk) {
      bh8 af[2], bf[8];
      const int ub = kk * 4 + fg;
#pragma unroll
      for (int mi = 0; mi < 2; ++mi) {
        int r = wm + mi * 16 + fr;
        af[mi] = *(const bh8*)(AsL + r * 64 + ((ub ^ swz8(r)) * 8));
      }
#pragma unroll
      for (int ni = 0; ni < 8; ++ni) {
        int r = wn + ni * 16 + fr;
        bf[ni] = *(const bh8*)(BsL + r * 64 + ((ub ^ swz8(r)) * 8));
      }
#pragma unroll
      for (int mi = 0; mi < 2; ++mi)
#pragma unroll
        for (int ni = 0; ni < 8; ++ni)
          acc[mi][ni] = __builtin_amdgcn_mfma_f32_16x16x32_bf16(af[mi], bf[ni], acc[mi][ni], 0, 0, 0);
    }
    __syncthreads();
  }
  // epilogue: v = acc + bias + src (residual); per-row stats
#pragma unroll
  for (int mi = 0; mi < 2; ++mi) {
#pragma unroll
    for (int r = 0; r < 4; ++r) {
      int rt = wm + mi * 16 + fg * 4 + r;
      long long gm = m0 + rt;
      float s = 0.f, q = 0.f;
#pragma unroll
      for (int ni = 0; ni < 8; ++ni) {
        int col = wn + ni * 16 + fr;
        float v = acc[mi][ni][r] + bias[col] + src[gm * 256 + col];
        acc[mi][ni][r] = v;
        s += v; q = fmaf(v, v, q);
      }
#pragma unroll
      for (int o = 1; o < 16; o <<= 1) { s += __shfl_xor(s, o); q += __shfl_xor(q, o); }
      if (fr == 0) { shS[rt][w & 1] = s; shQ[rt][w & 1] = q; }
    }
  }
  __syncthreads();
#pragma unroll
  for (int mi = 0; mi < 2; ++mi) {
#pragma unroll
    for (int r = 0; r < 4; ++r) {
      int rt = wm + mi * 16 + fg * 4 + r;
      long long gm = m0 + rt;
      float S = shS[rt][0] + shS[rt][1];
      float Q = shQ[rt][0] + shQ[rt][1];
      float mean = S * (1.f / 256.f);
      float var = Q * (1.f / 256.f) - mean * mean;
      float rstd = rsqrtf(var + 1e-5f);
      int prow = (int)(gm % NLEN);
#pragma unroll
      for (int ni = 0; ni < 8; ++ni) {
        int col = wn + ni * 16 + fr;
        float y = (acc[mi][ni][r] - mean) * rstd * ls[col] + lb[col];
        src[gm * 256 + col] = y;
        srcb[gm * 256 + col] = (bhalf)y;
        if (qbOut) qbOut[gm * 256 + col] = (bhalf)(y + pos[(long long)prow * 256 + col]);
      }
    }
  }
}

// =====================================================================
// Implicit-GEMM 3x3 conv, BK=64, K-order: c64-block-major / tap-inner.
// fpnT layout: [co][s*64 + c64l] with s = c64b*9 + tap.
// =====================================================================
__global__ __launch_bounds__(256) void bgemm_conv_kernel(
    const bhalf* __restrict__ Ab, const bhalf* __restrict__ Bt,
    bhalf* __restrict__ Cout)
{
  const int gx = gridDim.x, gy = gridDim.y;
  const int nwg = gx * gy * gridDim.z;
  int flat = (blockIdx.z * gy + blockIdx.y) * gx + blockIdx.x;
  int logical = xcd_swz(flat, nwg);
  const int bz = logical / (gx * gy);
  int rem = logical - bz * gx * gy;
  const int by = rem / gx;
  const int bx = rem - by * gx;

  const bhalf* Apad = Ab + (long long)bz * 37636 * 256;
  const int m0 = by * 128, n0 = bx * 128;
  __shared__ __align__(16) bhalf As[128 * 64];
  __shared__ __align__(16) bhalf Bs[128 * 64];
  const int t = threadIdx.x;
  const int lane = t & 63;
  const int w = t >> 6;
  const int wbase = t & 192;
  const int wm = (w >> 1) * 64, wn = (w & 1) * 64;
  const int fr = lane & 15, fg = lane >> 4;
  int rowA[4], py[4], px[4], kcg[4];
#pragma unroll
  for (int j = 0; j < 4; ++j) {
    int id = t + j * 256;
    rowA[j] = id >> 3;
    kcg[j] = (((id & 7) ^ swz8(rowA[j])) * 8);
    int m = m0 + rowA[j];
    py[j] = m / 192; px[j] = m % 192;
  }
  f32x4 acc[4][4] = {};
  for (int s = 0; s < 36; ++s) {
    const int c64b = s / 9, tap = s % 9;
    const int ty = tap / 3, tx = tap % 3;
#pragma unroll
    for (int j = 0; j < 4; ++j) {
      GLOAD_LDS16(Apad + ((long long)(py[j] + ty) * 194 + px[j] + tx) * 256 + c64b * 64 + kcg[j],
                  As + (wbase + j * 256) * 8);
      GLOAD_LDS16(Bt + (long long)(n0 + rowA[j]) * 2304 + s * 64 + kcg[j],
                  Bs + (wbase + j * 256) * 8);
    }
    __syncthreads();
#pragma unroll
    for (int kk = 0; kk < 2; ++kk) {
      bh8 af[4], bf[4];
      const int ub = kk * 4 + fg;
#pragma unroll
      for (int mi = 0; mi < 4; ++mi) {
        int r = wm + mi * 16 + fr;
        af[mi] = *(const bh8*)(As + r * 64 + ((ub ^ swz8(r)) * 8));
      }
#pragma unroll
      for (int ni = 0; ni < 4; ++ni) {
        int r = wn + ni * 16 + fr;
        bf[ni] = *(const bh8*)(Bs + r * 64 + ((ub ^ swz8(r)) * 8));
      }
#pragma unroll
      for (int mi = 0; mi < 4; ++mi)
#pragma unroll
        for (int ni = 0; ni < 4; ++ni)
          acc[mi][ni] = __builtin_amdgcn_mfma_f32_16x16x32_bf16(af[mi], bf[ni], acc[mi][ni], 0, 0, 0);
    }
    __syncthreads();
  }
  bhalf* Cb = Cout + (long long)bz * 36864 * 256;
#pragma unroll
  for (int mi = 0; mi < 4; ++mi)
#pragma unroll
    for (int r = 0; r < 4; ++r) {
      int m = m0 + wm + mi * 16 + fg * 4 + r;
#pragma unroll
      for (int ni = 0; ni < 4; ++ni) {
        int n = n0 + wn + ni * 16 + fr;
        Cb[(long long)m * 256 + n] = (bhalf)acc[mi][ni][r];
      }
    }
}

// =====================================================================
// Weight transpose+convert
// =====================================================================
__global__ void twcvt_kernel(const float* __restrict__ Wsrc, bhalf* __restrict__ out,
                             int Kd, int Nd, long long zdst)
{
  __shared__ float tile[32][33];
  long long zi = (long long)blockIdx.z * Kd * Nd;
  long long zo = (long long)blockIdx.z * zdst;
  int n0 = blockIdx.x * 32, k0 = blockIdx.y * 32;
#pragma unroll
  for (int j = 0; j < 4; ++j) {
    int kk = threadIdx.y + 8 * j;
    tile[kk][threadIdx.x] = Wsrc[zi + (long long)(k0 + kk) * Nd + n0 + threadIdx.x];
  }
  __syncthreads();
#pragma unroll
  for (int j = 0; j < 4; ++j) {
    int nn = threadIdx.y + 8 * j;
    out[zo + (long long)(n0 + nn) * Kd + k0 + threadIdx.x] = (bhalf)tile[threadIdx.x][nn];
  }
}

__global__ void tfeat_kernel(const float* __restrict__ Fsrc, bhalf* __restrict__ out,
                             int Ci, int HW)
{
  __shared__ float tile[32][33];
  long long zo = (long long)blockIdx.z * Ci * HW;
  int hw0 = blockIdx.x * 32, c0 = blockIdx.y * 32;
#pragma unroll
  for (int j = 0; j < 4; ++j) {
    int cc = threadIdx.y + 8 * j;
    tile[cc][threadIdx.x] = Fsrc[zo + (long long)(c0 + cc) * HW + hw0 + threadIdx.x];
  }
  __syncthreads();
#pragma unroll
  for (int j = 0; j < 4; ++j) {
    int hh = threadIdx.y + 8 * j;
    out[zo + (long long)(hw0 + hh) * Ci + c0 + threadIdx.x] = (bhalf)tile[threadIdx.x][hh];
  }
}

__global__ void cvt_kernel(const float* __restrict__ in, bhalf* __restrict__ out, int n)
{
  int i = blockIdx.x * 256 + threadIdx.x;
  if (i < n) out[i] = (bhalf)in[i];
}

// fpn_w [co][ci][9] -> fpnT[co][c64b*576 + tap*64 + c64l]
__global__ void fpnw_kernel(const float* __restrict__ Wsrc, bhalf* __restrict__ out)
{
  int o = blockIdx.x * 256 + threadIdx.x;
  if (o >= 256 * 2304) return;
  int co = o / 2304, r = o % 2304;
  int c64b = r / 576, rr = r % 576, tap = rr >> 6, c64l = rr & 63;
  int ci = c64b * 64 + c64l;
  out[o] = (bhalf)Wsrc[(co * 256 + ci) * 9 + tap];
}

__global__ void biascat_kernel(const float* __restrict__ ob, const float* __restrict__ ab,
                               float* __restrict__ out)
{
  int l = blockIdx.x, t = threadIdx.x;
  if (t < 288) out[l * 288 + t] = (t < 192) ? ob[l * 192 + t] : ab[l * 96 + t - 192];
}

__global__ void zero16_kernel(uint4* __restrict__ p, long long n16)
{
  long long i = (long long)blockIdx.x * 256 + threadIdx.x;
  if (i < n16) p[i] = make_uint4(0u, 0u, 0u, 0u);
}

// =====================================================================
// Sine positional embedding + level embed
// =====================================================================
__global__ void pos_kernel(float* __restrict__ pos, const float* __restrict__ level_embed)
{
  int i = blockIdx.x, c = threadIdx.x;
  int lvl, Wq, loc;
  if (i < 576)       { lvl = 0; Wq = 24; loc = i; }
  else if (i < 2880) { lvl = 1; Wq = 48; loc = i - 576; }
  else               { lvl = 2; Wq = 96; loc = i - 2880; }
  int h = loc / Wq, wcol = loc % Wq;
  int cc = c & 127;
  float coord = (c < 128) ? (float)(h + 1) : (float)(wcol + 1);
  float denom = (float)Wq + 1e-6f;
  float v = coord / denom * 6.28318530717958647692f;
  float tp = powf(10000.0f, (float)(cc & ~1) * (1.0f / 128.0f));
  float ang = v / tp;
  float val = (cc & 1) ? cosf(ang) : sinf(ang);
  pos[(long long)i * 256 + c] = val + level_embed[lvl * 256 + c];
}

// =====================================================================
// GN stats, two-pass, coalesced.
// =====================================================================
__global__ __launch_bounds__(256) void gn_part_kernel(const void* __restrict__ X,
    float* __restrict__ part, int HW, int isBf16, int nch)
{
  const int b = blockIdx.y, ch = blockIdx.x;
  const int rows = (HW + nch - 1) / nch;
  const int r0 = ch * rows;
  const int r1 = min(r0 + rows, HW);
  const int cg = threadIdx.x & 31;
  const int ro = threadIdx.x >> 5;
  float s = 0.f, s2 = 0.f;
  if (isBf16) {
    const bhalf* p = (const bhalf*)X + (long long)b * HW * 256 + cg * 8;
    for (int r = r0 + ro; r < r1; r += 8) {
      bh8 v = *(const bh8*)(p + (long long)r * 256);
#pragma unroll
      for (int j = 0; j < 8; ++j) { float f = (float)v[j]; s += f; s2 = fmaf(f, f, s2); }
    }
  } else {
    const float* p = (const float*)X + (long long)b * HW * 256 + cg * 8;
    for (int r = r0 + ro; r < r1; r += 8) {
      f32x4 v0 = *(const f32x4*)(p + (long long)r * 256);
      f32x4 v1 = *(const f32x4*)(p + (long long)r * 256 + 4);
#pragma unroll
      for (int j = 0; j < 4; ++j) { s += v0[j]; s2 = fmaf(v0[j], v0[j], s2); }
#pragma unroll
      for (int j = 0; j < 4; ++j) { s += v1[j]; s2 = fmaf(v1[j], v1[j], s2); }
    }
  }
  __shared__ float sh[2][8][32];
  sh[0][ro][cg] = s; sh[1][ro][cg] = s2;
  __syncthreads();
  if (threadIdx.x < 32) {
    float S = 0.f, S2 = 0.f;
#pragma unroll
    for (int k = 0; k < 8; ++k) { S += sh[0][k][threadIdx.x]; S2 += sh[1][k][threadIdx.x]; }
    long long o = ((long long)(b * 32 + threadIdx.x) * nch + ch) * 2;
    part[o] = S; part[o + 1] = S2;
  }
}

__global__ __launch_bounds__(64) void gn_fin_kernel(const float* __restrict__ part,
    float* __restrict__ stats, int nch, int HW)
{
  const int bg = blockIdx.x;
  float s = 0.f, s2 = 0.f;
  for (int i = threadIdx.x; i < nch; i += 64) {
    long long o = ((long long)bg * nch + i) * 2;
    s += part[o]; s2 += part[o + 1];
  }
#pragma unroll
  for (int o = 32; o > 0; o >>= 1) { s += __shfl_down(s, o); s2 += __shfl_down(s2, o); }
  if (threadIdx.x == 0) {
    float inv = 1.f / (float)(HW * 8);
    float mean = s * inv;
    float var = s2 * inv - mean * mean;
    stats[bg * 2] = mean;
    stats[bg * 2 + 1] = rsqrtf(var + 1e-5f);
  }
}

// =====================================================================
// GN apply -> src fp32 + srcb bf16 + qb bf16 (src+pos)
// =====================================================================
__global__ void gn_apply_rm_kernel(const float* __restrict__ T, const float* __restrict__ stats,
    const float* __restrict__ gs, const float* __restrict__ gb,
    float* __restrict__ src, bhalf* __restrict__ srcb, bhalf* __restrict__ qb,
    const float* __restrict__ pos, int HW, int startRow)
{
  long long idx = (long long)blockIdx.x * 256 + threadIdx.x;
  int c = threadIdx.x & 255;
  long long row = idx >> 8;
  int b = (int)(row / HW);
  long long hw = row - (long long)b * HW;
  int g = c >> 3;
  float v = T[idx];
  v = (v - stats[(b * 32 + g) * 2]) * stats[(b * 32 + g) * 2 + 1] * gs[c] + gb[c];
  long long pr = (startRow + hw) * 256 + c;
  long long o = (long long)b * NLEN * 256 + pr;
  src[o] = v;
  srcb[o] = (bhalf)v;
  qb[o] = (bhalf)(v + pos[pr]);
}

// =====================================================================
// MSDeformAttn sampling: 8 ch/lane (16B gathers), 32 lanes/query,
// fused softmax over 12 logits.
// =====================================================================
__global__ __launch_bounds__(256) void deform_kernel(const bhalf* __restrict__ value,
    const float* __restrict__ offaw, bhalf* __restrict__ out)
{
  const int t = threadIdx.x;
  const int q = t >> 5;
  const int sub = t & 31;
  const int bi = blockIdx.x * 8 + q;
  const int i = bi % NLEN;
  const int bbase = bi - i;
  const int c0 = sub * 8;
  const int head = sub >> 2;
  int loc, Wq;
  if (i < 576)       { Wq = 24; loc = i; }
  else if (i < 2880) { Wq = 48; loc = i - 576; }
  else               { Wq = 96; loc = i - 2880; }
  const float rx = ((loc % Wq) + 0.5f) / (float)Wq;
  const float ry = ((loc / Wq) + 0.5f) / (float)Wq;
  const float* offp = offaw + (long long)bi * 288 + head * 24;
  const float* awp  = offaw + (long long)bi * 288 + 192 + head * 12;
  float aw[12]; float mx = -1e30f;
#pragma unroll
  for (int j = 0; j < 12; ++j) { aw[j] = awp[j]; mx = fmaxf(mx, aw[j]); }
  float ssum = 0.f;
#pragma unroll
  for (int j = 0; j < 12; ++j) { aw[j] = __expf(aw[j] - mx); ssum += aw[j]; }
  const float sinv = 1.f / ssum;
  float acc[8] = {};
  const int starts[3] = {0, 576, 2880};
  const int Ls[3] = {24, 48, 96};
#pragma unroll
  for (int l = 0; l < 3; ++l) {
    const int Wl = Ls[l];
    const float fW = (float)Wl;
    const bhalf* vb = value + (long long)(bbase + starts[l]) * 256 + c0;
#pragma unroll
    for (int p = 0; p < 4; ++p) {
      const float ox = offp[l * 8 + p * 2], oy = offp[l * 8 + p * 2 + 1];
      const float a = aw[l * 4 + p] * sinv;
      const float x = (rx + ox / fW) * fW - 0.5f;
      const float y = (ry + oy / fW) * fW - 0.5f;
      const float x0f = floorf(x), y0f = floorf(y);
      const float wx = x - x0f, wy = y - y0f;
      const int x0 = (int)x0f, y0 = (int)y0f;
      const int x1 = x0 + 1, y1 = y0 + 1;
      const bool xv0 = (x0 >= 0) & (x0 < Wl);
      const bool xv1 = (x1 >= 0) & (x1 < Wl);
      const bool yv0 = (y0 >= 0) & (y0 < Wl);
      const bool yv1 = (y1 >= 0) & (y1 < Wl);
      const int cx0 = min(max(x0, 0), Wl - 1), cx1 = min(max(x1, 0), Wl - 1);
      const int cy0 = min(max(y0, 0), Wl - 1), cy1 = min(max(y1, 0), Wl - 1);
      const float w00 = (xv0 && yv0) ? (1.f - wx) * (1.f - wy) * a : 0.f;
      const float w01 = (xv1 && yv0) ? wx * (1.f - wy) * a : 0.f;
      const float w10 = (xv0 && yv1) ? (1.f - wx) * wy * a : 0.f;
      const float w11 = (xv1 && yv1) ? wx * wy * a : 0.f;
      const bh8 g00 = *(const bh8*)(vb + (cy0 * Wl + cx0) * 256);
      const bh8 g01 = *(const bh8*)(vb + (cy0 * Wl + cx1) * 256);
      const bh8 g10 = *(const bh8*)(vb + (cy1 * Wl + cx0) * 256);
      const bh8 g11 = *(const bh8*)(vb + (cy1 * Wl + cx1) * 256);
#pragma unroll
      for (int e = 0; e < 8; ++e)
        acc[e] = fmaf(w00, (float)g00[e], fmaf(w01, (float)g01[e],
                 fmaf(w10, (float)g10[e], fmaf(w11, (float)g11[e], acc[e]))));
    }
  }
  bh8 o;
#pragma unroll
  for (int e = 0; e < 8; ++e) o[e] = (bhalf)acc[e];
  *(bh8*)(out + (long long)bi * 256 + c0) = o;
}

// =====================================================================
// src[b][startRow+hw][c] -> out[b][c][hw]
// =====================================================================
__global__ void transpose_out_kernel(const float* __restrict__ src, float* __restrict__ out,
    int HW, int startRow)
{
  __shared__ float tile[32][33];
  int b = blockIdx.z;
  int w0 = blockIdx.x * 32, c0 = blockIdx.y * 32;
#pragma unroll
  for (int j = 0; j < 4; ++j) {
    int wl = threadIdx.y + 8 * j;
    tile[wl][threadIdx.x] = src[((long long)b * NLEN + startRow + w0 + wl) * 256 + c0 + threadIdx.x];
  }
  __syncthreads();
#pragma unroll
  for (int j = 0; j < 4; ++j) {
    int cl = threadIdx.y + 8 * j;
    out[((long long)b * 256 + c0 + cl) * HW + w0 + threadIdx.x] = tile[threadIdx.x][cl];
  }
}

// =====================================================================
// latb = GN(lat) + upsample2x(src lvl2), zero-padded layout
// =====================================================================
__global__ void lat_finish_rm_kernel(const bhalf* __restrict__ lat, const float* __restrict__ stats,
    const float* __restrict__ gs, const float* __restrict__ gb,
    const float* __restrict__ src, bhalf* __restrict__ latb)
{
  long long idx = (long long)blockIdx.x * 256 + threadIdx.x;
  int c = threadIdx.x & 255;
  long long row = idx >> 8;
  int b = (int)(row / 36864);
  int p = (int)(row - (long long)b * 36864);
  int y = p / 192, x = p % 192;
  int g = c >> 3;
  float v = (float)lat[idx];
  v = (v - stats[(b * 32 + g) * 2]) * stats[(b * 32 + g) * 2 + 1] * gs[c] + gb[c];
  float ys = fmaxf(y * 0.5f - 0.25f, 0.f);
  float xs = fmaxf(x * 0.5f - 0.25f, 0.f);
  int y0 = (int)ys; float wy = ys - (float)y0; int y1 = min(y0 + 1, 95);
  int x0 = (int)xs; float wx = xs - (float)x0; int x1 = min(x0 + 1, 95);
  const float* sp = src + ((long long)b * NLEN + 2880) * 256 + c;
  float r0 = sp[(long long)(y0 * 96 + x0) * 256] * (1.f - wx) + sp[(long long)(y0 * 96 + x1) * 256] * wx;
  float r1 = sp[(long long)(y1 * 96 + x0) * 256] * (1.f - wx) + sp[(long long)(y1 * 96 + x1) * 256] * wx;
  latb[((long long)b * 37636 + (long long)(y + 1) * 194 + (x + 1)) * 256 + c]
      = (bhalf)(v + r0 * (1.f - wy) + r1 * wy);
}

// =====================================================================
// Final GN+ReLU+transpose: convC bf16 [b][hw][c] -> Y fp32 [b][c][hw]
// =====================================================================
__global__ void gn_relu_tr_kernel(const bhalf* __restrict__ convC, const float* __restrict__ stats,
    const float* __restrict__ gs, const float* __restrict__ gb, float* __restrict__ Y)
{
  __shared__ float tile[32][33];
  int b = blockIdx.z;
  int hw0 = blockIdx.x * 32, c0 = blockIdx.y * 32;
#pragma unroll
  for (int j = 0; j < 4; ++j) {
    int hwl = threadIdx.y + 8 * j;
    int c = c0 + threadIdx.x;
    int g = c >> 3;
    float v = (float)convC[((long long)b * 36864 + hw0 + hwl) * 256 + c];
    v = (v - stats[(b * 32 + g) * 2]) * stats[(b * 32 + g) * 2 + 1] * gs[c] + gb[c];
    tile[hwl][threadIdx.x] = fmaxf(v, 0.f);
  }
  __syncthreads();
#pragma unroll
  for (int j = 0; j < 4; ++j) {
    int cl = threadIdx.y + 8 * j;
    Y[((long long)b * 256 + c0 + cl) * 36864 + hw0 + threadIdx.x] = tile[threadIdx.x][cl];
  }
}

// =====================================================================
extern "C" void kernel_launch(void* const* d_in, const int* in_sizes, int n_in,
                              void* d_out, int out_size, void* d_ws, size_t ws_size,
                              hipStream_t stream)
{
  const float* res2 = (const float*)d_in[0];
  const float* res3 = (const float*)d_in[1];
  const float* res4 = (const float*)d_in[2];
  const float* res5 = (const float*)d_in[3];
  const float* pw[3]  = {(const float*)d_in[4],  (const float*)d_in[8],  (const float*)d_in[12]};
  const float* pb[3]  = {(const float*)d_in[5],  (const float*)d_in[9],  (const float*)d_in[13]};
  const float* gss[3] = {(const float*)d_in[6],  (const float*)d_in[10], (const float*)d_in[14]};
  const float* gbb[3] = {(const float*)d_in[7],  (const float*)d_in[11], (const float*)d_in[15]};
  const float* level_embed = (const float*)d_in[16];
  const float* off_w = (const float*)d_in[17];
  const float* off_b = (const float*)d_in[18];
  const float* aw_w  = (const float*)d_in[19];
  const float* aw_b  = (const float*)d_in[20];
  const float* val_w = (const float*)d_in[21];
  const float* val_b = (const float*)d_in[22];
  const float* out_w = (const float*)d_in[23];
  const float* out_b = (const float*)d_in[24];
  const float* ln1_s = (const float*)d_in[25];
  const float* ln1_b = (const float*)d_in[26];
  const float* ffn1_w = (const float*)d_in[27];
  const float* ffn1_b = (const float*)d_in[28];
  const float* ffn2_w = (const float*)d_in[29];
  const float* ffn2_b = (const float*)d_in[30];
  const float* ln2_s = (const float*)d_in[31];
  const float* ln2_b = (const float*)d_in[32];
  const float* lat_w = (const float*)d_in[33];
  const float* lat_gs = (const float*)d_in[34];
  const float* lat_gb = (const float*)d_in[35];
  const float* fpn_w = (const float*)d_in[36];
  const float* fpn_gs = (const float*)d_in[37];
  const float* fpn_gb = (const float*)d_in[38];

  char* W = (char*)d_ws;
  float* src   = (float*)(W + 0);
  float* pos   = (float*)(W + 24772608LL);
  float* tmp   = (float*)(W + 37158912LL);
  bhalf* srcb  = (bhalf*)(W + 61931520LL);
  bhalf* wreg  = (bhalf*)(W + 74317824LL);
  float* stats = (float*)(W + 86212608LL);
  float* part  = (float*)(W + 86213120LL);
  float* offaw_b = (float*)(W + 86278656LL);
  char*  U     = W + 86286848LL;

  bhalf* valT   = wreg + 0;
  bhalf* offawT = wreg + 393216;
  bhalf* outT   = wreg + 835584;
  bhalf* f1T    = wreg + 1228800;
  bhalf* f2T    = wreg + 2801664;
  bhalf* pwb5   = wreg + 4374528;
  bhalf* pwb4   = wreg + 4898816;
  bhalf* pwb3   = wreg + 5160960;
  bhalf* latwb  = wreg + 5292032;
  bhalf* fpnT   = wreg + 5357568;

  bhalf* qb      = (bhalf*)(U + 0);
  bhalf* valueb  = (bhalf*)(U + 12386304LL);
  bhalf* sampb   = (bhalf*)(U + 24772608LL);
  float* offbuf  = (float*)(U + 37158912LL);
  bhalf* hbuf    = (bhalf*)(U + 65028096LL);
  bhalf* featT   = (bhalf*)(U + 24772608LL);   // projection-phase only
  bhalf* res2T   = (bhalf*)(U + 0);
  bhalf* latbf   = (bhalf*)(U + 37748736LL);
  bhalf* latb    = (bhalf*)(U + 75497472LL);

  float* Yout = (float*)d_out;
  float* out0 = Yout + 18874368LL;
  float* out1 = Yout + 19169280LL;
  float* out2 = Yout + 20348928LL;

  const int M = BB * NLEN;  // 24192

  // ---- weight prep ----
  twcvt_kernel<<<dim3(8, 8, 6), dim3(32, 8), 0, stream>>>(val_w, valT, 256, 256, 65536LL);
  twcvt_kernel<<<dim3(6, 8, 6), dim3(32, 8), 0, stream>>>(off_w, offawT, 256, 192, 73728LL);
  twcvt_kernel<<<dim3(3, 8, 6), dim3(32, 8), 0, stream>>>(aw_w, offawT + 192 * 256, 256, 96, 73728LL);
  twcvt_kernel<<<dim3(8, 8, 6), dim3(32, 8), 0, stream>>>(out_w, outT, 256, 256, 65536LL);
  twcvt_kernel<<<dim3(32, 8, 6), dim3(32, 8), 0, stream>>>(ffn1_w, f1T, 256, 1024, 262144LL);
  twcvt_kernel<<<dim3(8, 32, 6), dim3(32, 8), 0, stream>>>(ffn2_w, f2T, 1024, 256, 262144LL);
  biascat_kernel<<<dim3(6), dim3(288), 0, stream>>>(off_b, aw_b, offaw_b);
  cvt_kernel<<<dim3(2048), dim3(256), 0, stream>>>(pw[0], pwb5, 524288);
  cvt_kernel<<<dim3(1024), dim3(256), 0, stream>>>(pw[1], pwb4, 262144);
  cvt_kernel<<<dim3(512),  dim3(256), 0, stream>>>(pw[2], pwb3, 131072);
  cvt_kernel<<<dim3(256),  dim3(256), 0, stream>>>(lat_w, latwb, 65536);
  fpnw_kernel<<<dim3(2304), dim3(256), 0, stream>>>(fpn_w, fpnT);

  // ---- positional embedding ----
  pos_kernel<<<dim3(NLEN), dim3(256), 0, stream>>>(pos, level_embed);

  // ---- input projections + GN -> src/srcb/qb ----
  const float* feats[3] = {res5, res4, res3};
  const bhalf* pwbs[3] = {pwb5, pwb4, pwb3};
  const int cins[3] = {2048, 1024, 512};
  const int HWs[3] = {576, 2304, 9216};
  const int startsHost[3] = {0, 576, 2880};
  const int nchs[3] = {16, 64, 128};
  for (int lvl = 0; lvl < 3; ++lvl) {
    int HW = HWs[lvl], cin = cins[lvl], nch = nchs[lvl];
    tfeat_kernel<<<dim3(HW / 32, cin / 32, BB), dim3(32, 8), 0, stream>>>(feats[lvl], featT, cin, HW);
    bgemm_kernel<<<dim3(2, (HW + 127) / 128, BB), dim3(256), 0, stream>>>(
        featT, pwbs[lvl], pb[lvl], tmp, HW, 256, cin,
        (long long)HW * cin, 0LL, (long long)HW * 256, 0, 0);
    gn_part_kernel<<<dim3(nch, BB), dim3(256), 0, stream>>>(tmp, part, HW, 0, nch);
    gn_fin_kernel<<<dim3(64), dim3(64), 0, stream>>>(part, stats, nch, HW);
    gn_apply_rm_kernel<<<dim3(BB * HW), dim3(256), 0, stream>>>(
        tmp, stats, gss[lvl], gbb[lvl], src, srcb, qb, pos, HW, startsHost[lvl]);
  }

  // ---- 6 encoder layers ----
  for (int l = 0; l < 6; ++l) {
    bgemm_kernel<<<dim3(2, M / 128, 1), dim3(256), 0, stream>>>(
        srcb, valT + (long long)l * 65536, val_b + l * 256, valueb,
        M, 256, 256, 0LL, 0LL, 0LL, 1, 0);
    bgemm_kernel<<<dim3(3, M / 128, 1), dim3(256), 0, stream>>>(
        qb, offawT + (long long)l * 73728, offaw_b + l * 288, offbuf,
        M, 288, 256, 0LL, 0LL, 0LL, 0, 0);
    deform_kernel<<<dim3(M / 8), dim3(256), 0, stream>>>(valueb, offbuf, sampb);
    // out-proj + residual + LN1 (fused)
    bgemm_ln_kernel<<<dim3(M / 64), dim3(256), 0, stream>>>(
        sampb, outT + (long long)l * 65536, out_b + l * 256,
        src, srcb, nullptr, pos, ln1_s + l * 256, ln1_b + l * 256, M, 256);
    bgemm_kernel<<<dim3(8, M / 128, 1), dim3(256), 0, stream>>>(
        srcb, f1T + (long long)l * 262144, ffn1_b + l * 1024, hbuf,
        M, 1024, 256, 0LL, 0LL, 0LL, 1, 1);
    // ffn2 + residual + LN2 (fused, also emits qb = y + pos)
    bgemm_ln_kernel<<<dim3(M / 64), dim3(256), 0, stream>>>(
        hbuf, f2T + (long long)l * 262144, ffn2_b + l * 256,
        src, srcb, qb, pos, ln2_s + l * 256, ln2_b + l * 256, M, 1024);
  }

  // ---- output transposes ----
  float* outsPtr[3] = {out0, out1, out2};
  for (int lvl = 0; lvl < 3; ++lvl) {
    transpose_out_kernel<<<dim3(HWs[lvl] / 32, 8, BB), dim3(32, 8), 0, stream>>>(
        src, outsPtr[lvl], HWs[lvl], startsHost[lvl]);
  }

  // ---- FPN ----
  tfeat_kernel<<<dim3(1152, 8, BB), dim3(32, 8), 0, stream>>>(res2, res2T, 256, 36864);
  bgemm_kernel<<<dim3(2, 288, BB), dim3(256), 0, stream>>>(
      res2T, latwb, nullptr, latbf, 36864, 256, 256,
      36864LL * 256, 0LL, 36864LL * 256, 1, 0);
  gn_part_kernel<<<dim3(128, BB), dim3(256), 0, stream>>>(latbf, part, 36864, 1, 128);
  gn_fin_kernel<<<dim3(64), dim3(64), 0, stream>>>(part, stats, 128, 36864);
  zero16_kernel<<<dim3(9410), dim3(256), 0, stream>>>((uint4*)latb, 2408704LL);
  lat_finish_rm_kernel<<<dim3(73728), dim3(256), 0, stream>>>(latbf, stats, lat_gs, lat_gb, src, latb);
  bgemm_conv_kernel<<<dim3(2, 288, BB), dim3(256), 0, stream>>>(latb, fpnT, latbf);
  gn_part_kernel<<<dim3(128, BB), dim3(256), 0, stream>>>(latbf, part, 36864, 1, 128);
  gn_fin_kernel<<<dim3(64), dim3(64), 0, stream>>>(part, stats, 128, 36864);
  gn_relu_tr_kernel<<<dim3(1152, 8, BB), dim3(32, 8), 0, stream>>>(latbf, stats, fpn_gs, fpn_gb, Yout);
}

// Round 12
// 1771.298 us; speedup vs baseline: 1.0399x; 1.0399x over previous
//
#include <hip/hip_runtime.h>
#include <math.h>

#define NLEN 12096
#define BB 2

typedef __bf16 bhalf;
typedef bhalf bh8 __attribute__((ext_vector_type(8)));
typedef bhalf bh4 __attribute__((ext_vector_type(4)));
typedef float f32x4 __attribute__((ext_vector_type(4)));

// LDS 16B-slot swizzle (verified round 8: bank conflicts -> 0). BK=32.
__device__ __forceinline__ int swz(int row) { return (row >> 1) & 3; }

// Bijective XCD-chunk swizzle (T1, m204).
__device__ __forceinline__ int xcd_swz(int id, int nwg) {
  int q = nwg >> 3, r = nwg & 7;
  int xcd = id & 7, pos = id >> 3;
  int base = (xcd < r) ? xcd * (q + 1) : r * (q + 1) + (xcd - r) * q;
  return base + pos;
}

#define GLOAD_LDS16(g, l) \
  __builtin_amdgcn_global_load_lds( \
      (const __attribute__((address_space(1))) unsigned int*)(g), \
      (__attribute__((address_space(3))) unsigned int*)(l), 16, 0, 0)

// =====================================================================
// bf16 MFMA GEMM: C[M,N] = A[M,K] @ Bt[N,K]^T  (+bias[n]) (+relu)
// Tile 128x128, BK=32 (round-11 lesson: BK=64 regressed via occupancy).
// =====================================================================
__global__ __launch_bounds__(256) void bgemm_kernel(
    const bhalf* __restrict__ A, const bhalf* __restrict__ Bt,
    const float* __restrict__ bias, void* __restrict__ Cout,
    int M, int N, int K, long long sA, long long sB, long long sC,
    int outBf16, int relu)
{
  const int gx = gridDim.x, gy = gridDim.y;
  const int nwg = gx * gy * gridDim.z;
  int flat = (blockIdx.z * gy + blockIdx.y) * gx + blockIdx.x;
  int logical = xcd_swz(flat, nwg);
  const int bz = logical / (gx * gy);
  int rem = logical - bz * gx * gy;
  const int by = rem / gx;
  const int bx = rem - by * gx;

  A += bz * sA; Bt += bz * sB;
  const int m0 = by * 128, n0 = bx * 128;
  __shared__ __align__(16) bhalf As[128 * 32];
  __shared__ __align__(16) bhalf Bs[128 * 32];
  const int t = threadIdx.x;
  const int lane = t & 63;
  const int w = t >> 6;
  const int wbase = t & 192;
  const int wm = (w >> 1) * 64, wn = (w & 1) * 64;
  const int fr = lane & 15, fg = lane >> 4;
  f32x4 acc[4][4] = {};
  for (int k0 = 0; k0 < K; k0 += 32) {
#pragma unroll
    for (int j = 0; j < 2; ++j) {
      int id = t + j * 256;
      int row = id >> 2, up = id & 3;
      int kcg = ((up ^ swz(row)) * 8);
      int m = m0 + row; m = (m < M) ? m : (M - 1);
      GLOAD_LDS16(A + (long long)m * K + k0 + kcg, As + (wbase + j * 256) * 8);
      int n = n0 + row; n = (n < N) ? n : (N - 1);
      GLOAD_LDS16(Bt + (long long)n * K + k0 + kcg, Bs + (wbase + j * 256) * 8);
    }
    __syncthreads();
    bh8 af[4], bf[4];
#pragma unroll
    for (int mi = 0; mi < 4; ++mi) {
      int r = wm + mi * 16 + fr;
      af[mi] = *(const bh8*)(As + r * 32 + ((fg ^ swz(r)) * 8));
    }
#pragma unroll
    for (int ni = 0; ni < 4; ++ni) {
      int r = wn + ni * 16 + fr;
      bf[ni] = *(const bh8*)(Bs + r * 32 + ((fg ^ swz(r)) * 8));
    }
#pragma unroll
    for (int mi = 0; mi < 4; ++mi)
#pragma unroll
      for (int ni = 0; ni < 4; ++ni)
        acc[mi][ni] = __builtin_amdgcn_mfma_f32_16x16x32_bf16(af[mi], bf[ni], acc[mi][ni], 0, 0, 0);
    __syncthreads();
  }
  float* Cf = (float*)Cout + bz * sC;
  bhalf* Cb = (bhalf*)Cout + bz * sC;
#pragma unroll
  for (int mi = 0; mi < 4; ++mi) {
#pragma unroll
    for (int r = 0; r < 4; ++r) {
      int m = m0 + wm + mi * 16 + fg * 4 + r;
      if (m >= M) continue;
#pragma unroll
      for (int ni = 0; ni < 4; ++ni) {
        int n = n0 + wn + ni * 16 + fr;
        if (n >= N) continue;
        float v = acc[mi][ni][r];
        if (bias) v += bias[n];
        if (relu) v = fmaxf(v, 0.f);
        if (outBf16) Cb[(long long)m * N + n] = (bhalf)v;
        else         Cf[(long long)m * N + n] = v;
      }
    }
  }
}

// =====================================================================
// Fused GEMM + bias + residual + LayerNorm. Tile 64x256, BK=32.
// =====================================================================
__global__ __launch_bounds__(256) void bgemm_ln_kernel(
    const bhalf* __restrict__ A, const bhalf* __restrict__ Bt,
    const float* __restrict__ bias,
    float* __restrict__ src, bhalf* __restrict__ srcb,
    bhalf* __restrict__ qbOut, const float* __restrict__ pos,
    const float* __restrict__ ls, const float* __restrict__ lb,
    int M, int K)
{
  const int nwg = gridDim.x;
  const int bid = xcd_swz(blockIdx.x, nwg);
  const int m0 = bid * 64;
  __shared__ __align__(16) bhalf Ls[320 * 32];
  bhalf* AsL = Ls;
  bhalf* BsL = Ls + 64 * 32;
  __shared__ float shS[64][2], shQ[64][2];
  const int t = threadIdx.x;
  const int lane = t & 63;
  const int w = t >> 6;
  const int wbase = t & 192;
  const int wm = (w >> 1) * 32, wn = (w & 1) * 128;
  const int fr = lane & 15, fg = lane >> 4;
  f32x4 acc[2][8] = {};
  for (int k0 = 0; k0 < K; k0 += 32) {
#pragma unroll
    for (int j = 0; j < 5; ++j) {
      int id = t + j * 256;
      int row = id >> 2, up = id & 3;
      int kcg = ((up ^ swz(row)) * 8);
      const bhalf* gsrc = (row < 64)
          ? (A + (long long)(m0 + row) * K + k0 + kcg)
          : (Bt + (long long)(row - 64) * K + k0 + kcg);
      GLOAD_LDS16(gsrc, Ls + (wbase + j * 256) * 8);
    }
    __syncthreads();
    bh8 af[2], bf[8];
#pragma unroll
    for (int mi = 0; mi < 2; ++mi) {
      int r = wm + mi * 16 + fr;
      af[mi] = *(const bh8*)(AsL + r * 32 + ((fg ^ swz(r)) * 8));
    }
#pragma unroll
    for (int ni = 0; ni < 8; ++ni) {
      int r = wn + ni * 16 + fr;
      bf[ni] = *(const bh8*)(BsL + r * 32 + ((fg ^ swz(r)) * 8));
    }
#pragma unroll
    for (int mi = 0; mi < 2; ++mi)
#pragma unroll
      for (int ni = 0; ni < 8; ++ni)
        acc[mi][ni] = __builtin_amdgcn_mfma_f32_16x16x32_bf16(af[mi], bf[ni], acc[mi][ni], 0, 0, 0);
    __syncthreads();
  }
#pragma unroll
  for (int mi = 0; mi < 2; ++mi) {
#pragma unroll
    for (int r = 0; r < 4; ++r) {
      int rt = wm + mi * 16 + fg * 4 + r;
      long long gm = m0 + rt;
      float s = 0.f, q = 0.f;
#pragma unroll
      for (int ni = 0; ni < 8; ++ni) {
        int col = wn + ni * 16 + fr;
        float v = acc[mi][ni][r] + bias[col] + src[gm * 256 + col];
        acc[mi][ni][r] = v;
        s += v; q = fmaf(v, v, q);
      }
#pragma unroll
      for (int o = 1; o < 16; o <<= 1) { s += __shfl_xor(s, o); q += __shfl_xor(q, o); }
      if (fr == 0) { shS[rt][w & 1] = s; shQ[rt][w & 1] = q; }
    }
  }
  __syncthreads();
#pragma unroll
  for (int mi = 0; mi < 2; ++mi) {
#pragma unroll
    for (int r = 0; r < 4; ++r) {
      int rt = wm + mi * 16 + fg * 4 + r;
      long long gm = m0 + rt;
      float S = shS[rt][0] + shS[rt][1];
      float Q = shQ[rt][0] + shQ[rt][1];
      float mean = S * (1.f / 256.f);
      float var = Q * (1.f / 256.f) - mean * mean;
      float rstd = rsqrtf(var + 1e-5f);
      int prow = (int)(gm % NLEN);
#pragma unroll
      for (int ni = 0; ni < 8; ++ni) {
        int col = wn + ni * 16 + fr;
        float y = (acc[mi][ni][r] - mean) * rstd * ls[col] + lb[col];
        src[gm * 256 + col] = y;
        srcb[gm * 256 + col] = (bhalf)y;
        if (qbOut) qbOut[gm * 256 + col] = (bhalf)(y + pos[(long long)prow * 256 + col]);
      }
    }
  }
}

// =====================================================================
// Implicit-GEMM 3x3 conv, BK=32, ci_block-major / tap-inner (round 10).
// =====================================================================
__global__ __launch_bounds__(256) void bgemm_conv_kernel(
    const bhalf* __restrict__ Ab, const bhalf* __restrict__ Bt,
    bhalf* __restrict__ Cout)
{
  const int gx = gridDim.x, gy = gridDim.y;
  const int nwg = gx * gy * gridDim.z;
  int flat = (blockIdx.z * gy + blockIdx.y) * gx + blockIdx.x;
  int logical = xcd_swz(flat, nwg);
  const int bz = logical / (gx * gy);
  int rem = logical - bz * gx * gy;
  const int by = rem / gx;
  const int bx = rem - by * gx;

  const bhalf* Apad = Ab + (long long)bz * 37636 * 256;
  const int m0 = by * 128, n0 = bx * 128;
  __shared__ __align__(16) bhalf As[128 * 32];
  __shared__ __align__(16) bhalf Bs[128 * 32];
  const int t = threadIdx.x;
  const int lane = t & 63;
  const int w = t >> 6;
  const int wbase = t & 192;
  const int wm = (w >> 1) * 64, wn = (w & 1) * 64;
  const int fr = lane & 15, fg = lane >> 4;
  int rowA[2], py[2], px[2], kcg[2];
#pragma unroll
  for (int j = 0; j < 2; ++j) {
    int id = t + j * 256;
    rowA[j] = id >> 2;
    kcg[j] = (((id & 3) ^ swz(rowA[j])) * 8);
    int m = m0 + rowA[j];
    py[j] = m / 192; px[j] = m % 192;
  }
  f32x4 acc[4][4] = {};
  for (int s = 0; s < 72; ++s) {
    const int cib = s / 9, tap = s % 9;
    const int ty = tap / 3, tx = tap % 3;
#pragma unroll
    for (int j = 0; j < 2; ++j) {
      GLOAD_LDS16(Apad + ((long long)(py[j] + ty) * 194 + px[j] + tx) * 256 + cib * 32 + kcg[j],
                  As + (wbase + j * 256) * 8);
      GLOAD_LDS16(Bt + (long long)(n0 + rowA[j]) * 2304 + s * 32 + kcg[j],
                  Bs + (wbase + j * 256) * 8);
    }
    __syncthreads();
    bh8 af[4], bf[4];
#pragma unroll
    for (int mi = 0; mi < 4; ++mi) {
      int r = wm + mi * 16 + fr;
      af[mi] = *(const bh8*)(As + r * 32 + ((fg ^ swz(r)) * 8));
    }
#pragma unroll
    for (int ni = 0; ni < 4; ++ni) {
      int r = wn + ni * 16 + fr;
      bf[ni] = *(const bh8*)(Bs + r * 32 + ((fg ^ swz(r)) * 8));
    }
#pragma unroll
    for (int mi = 0; mi < 4; ++mi)
#pragma unroll
      for (int ni = 0; ni < 4; ++ni)
        acc[mi][ni] = __builtin_amdgcn_mfma_f32_16x16x32_bf16(af[mi], bf[ni], acc[mi][ni], 0, 0, 0);
    __syncthreads();
  }
  bhalf* Cb = Cout + (long long)bz * 36864 * 256;
#pragma unroll
  for (int mi = 0; mi < 4; ++mi)
#pragma unroll
    for (int r = 0; r < 4; ++r) {
      int m = m0 + wm + mi * 16 + fg * 4 + r;
#pragma unroll
      for (int ni = 0; ni < 4; ++ni) {
        int n = n0 + wn + ni * 16 + fr;
        Cb[(long long)m * 256 + n] = (bhalf)acc[mi][ni][r];
      }
    }
}

// =====================================================================
// Weight transpose+convert
// =====================================================================
__global__ void twcvt_kernel(const float* __restrict__ Wsrc, bhalf* __restrict__ out,
                             int Kd, int Nd, long long zdst)
{
  __shared__ float tile[32][33];
  long long zi = (long long)blockIdx.z * Kd * Nd;
  long long zo = (long long)blockIdx.z * zdst;
  int n0 = blockIdx.x * 32, k0 = blockIdx.y * 32;
#pragma unroll
  for (int j = 0; j < 4; ++j) {
    int kk = threadIdx.y + 8 * j;
    tile[kk][threadIdx.x] = Wsrc[zi + (long long)(k0 + kk) * Nd + n0 + threadIdx.x];
  }
  __syncthreads();
#pragma unroll
  for (int j = 0; j < 4; ++j) {
    int nn = threadIdx.y + 8 * j;
    out[zo + (long long)(n0 + nn) * Kd + k0 + threadIdx.x] = (bhalf)tile[threadIdx.x][nn];
  }
}

__global__ void tfeat_kernel(const float* __restrict__ Fsrc, bhalf* __restrict__ out,
                             int Ci, int HW)
{
  __shared__ float tile[32][33];
  long long zo = (long long)blockIdx.z * Ci * HW;
  int hw0 = blockIdx.x * 32, c0 = blockIdx.y * 32;
#pragma unroll
  for (int j = 0; j < 4; ++j) {
    int cc = threadIdx.y + 8 * j;
    tile[cc][threadIdx.x] = Fsrc[zo + (long long)(c0 + cc) * HW + hw0 + threadIdx.x];
  }
  __syncthreads();
#pragma unroll
  for (int j = 0; j < 4; ++j) {
    int hh = threadIdx.y + 8 * j;
    out[zo + (long long)(hw0 + hh) * Ci + c0 + threadIdx.x] = (bhalf)tile[threadIdx.x][hh];
  }
}

__global__ void cvt_kernel(const float* __restrict__ in, bhalf* __restrict__ out, int n)
{
  int i = blockIdx.x * 256 + threadIdx.x;
  if (i < n) out[i] = (bhalf)in[i];
}

// fpn_w [co][ci][9] -> fpnT[co][cib*288 + tap*32 + cil]
__global__ void fpnw_kernel(const float* __restrict__ Wsrc, bhalf* __restrict__ out)
{
  int o = blockIdx.x * 256 + threadIdx.x;
  if (o >= 256 * 2304) return;
  int co = o / 2304, r = o % 2304;
  int cib = r / 288, rr = r % 288, tap = rr >> 5, cil = rr & 31;
  int ci = cib * 32 + cil;
  out[o] = (bhalf)Wsrc[(co * 256 + ci) * 9 + tap];
}

__global__ void biascat_kernel(const float* __restrict__ ob, const float* __restrict__ ab,
                               float* __restrict__ out)
{
  int l = blockIdx.x, t = threadIdx.x;
  if (t < 288) out[l * 288 + t] = (t < 192) ? ob[l * 192 + t] : ab[l * 96 + t - 192];
}

// zero only the 1-px border of the padded [B][194*194][256] bf16 buffer
// (interior is fully overwritten by lat_finish every launch).
__global__ void border_zero_kernel(bhalf* __restrict__ latb)
{
  // 4 strips: row 0, row 193, col 0, col 193 -> 4*194 = 776 positions/batch
  int idx = blockIdx.x * 256 + threadIdx.x;   // position*2 batches covered by grid
  int total = BB * 4 * 194;
  if (idx >= total) return;
  int b = idx / (4 * 194);
  int r = idx - b * 4 * 194;
  int strip = r / 194, p = r % 194;
  int y, x;
  if (strip == 0)      { y = 0;   x = p; }
  else if (strip == 1) { y = 193; x = p; }
  else if (strip == 2) { y = p;   x = 0; }
  else                 { y = p;   x = 193; }
  uint4* dst = (uint4*)(latb + ((long long)b * 37636 + (long long)y * 194 + x) * 256);
#pragma unroll
  for (int j = 0; j < 32; ++j) dst[j] = make_uint4(0u, 0u, 0u, 0u);
}

// =====================================================================
// Sine positional embedding + level embed
// =====================================================================
__global__ void pos_kernel(float* __restrict__ pos, const float* __restrict__ level_embed)
{
  int i = blockIdx.x, c = threadIdx.x;
  int lvl, Wq, loc;
  if (i < 576)       { lvl = 0; Wq = 24; loc = i; }
  else if (i < 2880) { lvl = 1; Wq = 48; loc = i - 576; }
  else               { lvl = 2; Wq = 96; loc = i - 2880; }
  int h = loc / Wq, wcol = loc % Wq;
  int cc = c & 127;
  float coord = (c < 128) ? (float)(h + 1) : (float)(wcol + 1);
  float denom = (float)Wq + 1e-6f;
  float v = coord / denom * 6.28318530717958647692f;
  float tp = powf(10000.0f, (float)(cc & ~1) * (1.0f / 128.0f));
  float ang = v / tp;
  float val = (cc & 1) ? cosf(ang) : sinf(ang);
  pos[(long long)i * 256 + c] = val + level_embed[lvl * 256 + c];
}

// =====================================================================
// GN stats, two-pass, coalesced.
// =====================================================================
__global__ __launch_bounds__(256) void gn_part_kernel(const void* __restrict__ X,
    float* __restrict__ part, int HW, int isBf16, int nch)
{
  const int b = blockIdx.y, ch = blockIdx.x;
  const int rows = (HW + nch - 1) / nch;
  const int r0 = ch * rows;
  const int r1 = min(r0 + rows, HW);
  const int cg = threadIdx.x & 31;
  const int ro = threadIdx.x >> 5;
  float s = 0.f, s2 = 0.f;
  if (isBf16) {
    const bhalf* p = (const bhalf*)X + (long long)b * HW * 256 + cg * 8;
    for (int r = r0 + ro; r < r1; r += 8) {
      bh8 v = *(const bh8*)(p + (long long)r * 256);
#pragma unroll
      for (int j = 0; j < 8; ++j) { float f = (float)v[j]; s += f; s2 = fmaf(f, f, s2); }
    }
  } else {
    const float* p = (const float*)X + (long long)b * HW * 256 + cg * 8;
    for (int r = r0 + ro; r < r1; r += 8) {
      f32x4 v0 = *(const f32x4*)(p + (long long)r * 256);
      f32x4 v1 = *(const f32x4*)(p + (long long)r * 256 + 4);
#pragma unroll
      for (int j = 0; j < 4; ++j) { s += v0[j]; s2 = fmaf(v0[j], v0[j], s2); }
#pragma unroll
      for (int j = 0; j < 4; ++j) { s += v1[j]; s2 = fmaf(v1[j], v1[j], s2); }
    }
  }
  __shared__ float sh[2][8][32];
  sh[0][ro][cg] = s; sh[1][ro][cg] = s2;
  __syncthreads();
  if (threadIdx.x < 32) {
    float S = 0.f, S2 = 0.f;
#pragma unroll
    for (int k = 0; k < 8; ++k) { S += sh[0][k][threadIdx.x]; S2 += sh[1][k][threadIdx.x]; }
    long long o = ((long long)(b * 32 + threadIdx.x) * nch + ch) * 2;
    part[o] = S; part[o + 1] = S2;
  }
}

__global__ __launch_bounds__(64) void gn_fin_kernel(const float* __restrict__ part,
    float* __restrict__ stats, int nch, int HW)
{
  const int bg = blockIdx.x;
  float s = 0.f, s2 = 0.f;
  for (int i = threadIdx.x; i < nch; i += 64) {
    long long o = ((long long)bg * nch + i) * 2;
    s += part[o]; s2 += part[o + 1];
  }
#pragma unroll
  for (int o = 32; o > 0; o >>= 1) { s += __shfl_down(s, o); s2 += __shfl_down(s2, o); }
  if (threadIdx.x == 0) {
    float inv = 1.f / (float)(HW * 8);
    float mean = s * inv;
    float var = s2 * inv - mean * mean;
    stats[bg * 2] = mean;
    stats[bg * 2 + 1] = rsqrtf(var + 1e-5f);
  }
}

// =====================================================================
// GN apply -> src fp32 + srcb bf16 + qb bf16 (src+pos)
// =====================================================================
__global__ void gn_apply_rm_kernel(const float* __restrict__ T, const float* __restrict__ stats,
    const float* __restrict__ gs, const float* __restrict__ gb,
    float* __restrict__ src, bhalf* __restrict__ srcb, bhalf* __restrict__ qb,
    const float* __restrict__ pos, int HW, int startRow)
{
  long long idx = (long long)blockIdx.x * 256 + threadIdx.x;
  int c = threadIdx.x & 255;
  long long row = idx >> 8;
  int b = (int)(row / HW);
  long long hw = row - (long long)b * HW;
  int g = c >> 3;
  float v = T[idx];
  v = (v - stats[(b * 32 + g) * 2]) * stats[(b * 32 + g) * 2 + 1] * gs[c] + gb[c];
  long long pr = (startRow + hw) * 256 + c;
  long long o = (long long)b * NLEN * 256 + pr;
  src[o] = v;
  srcb[o] = (bhalf)v;
  qb[o] = (bhalf)(v + pos[pr]);
}

// =====================================================================
// MSDeformAttn sampling: 8 ch/lane (16B gathers), 32 lanes/query,
// fused softmax over 12 logits. offaw now bf16 [B*LEN][288].
// =====================================================================
__global__ __launch_bounds__(256) void deform_kernel(const bhalf* __restrict__ value,
    const bhalf* __restrict__ offaw, bhalf* __restrict__ out)
{
  const int t = threadIdx.x;
  const int q = t >> 5;
  const int sub = t & 31;
  const int bi = blockIdx.x * 8 + q;
  const int i = bi % NLEN;
  const int bbase = bi - i;
  const int c0 = sub * 8;
  const int head = sub >> 2;
  int loc, Wq;
  if (i < 576)       { Wq = 24; loc = i; }
  else if (i < 2880) { Wq = 48; loc = i - 576; }
  else               { Wq = 96; loc = i - 2880; }
  const float rx = ((loc % Wq) + 0.5f) / (float)Wq;
  const float ry = ((loc / Wq) + 0.5f) / (float)Wq;
  const bhalf* offp = offaw + (long long)bi * 288 + head * 24;
  const bhalf* awp  = offaw + (long long)bi * 288 + 192 + head * 12;
  float aw[12]; float mx = -1e30f;
#pragma unroll
  for (int j = 0; j < 12; ++j) { aw[j] = (float)awp[j]; mx = fmaxf(mx, aw[j]); }
  float ssum = 0.f;
#pragma unroll
  for (int j = 0; j < 12; ++j) { aw[j] = __expf(aw[j] - mx); ssum += aw[j]; }
  const float sinv = 1.f / ssum;
  float acc[8] = {};
  const int starts[3] = {0, 576, 2880};
  const int Ls[3] = {24, 48, 96};
#pragma unroll
  for (int l = 0; l < 3; ++l) {
    const int Wl = Ls[l];
    const float fW = (float)Wl;
    const bhalf* vb = value + (long long)(bbase + starts[l]) * 256 + c0;
#pragma unroll
    for (int p = 0; p < 4; ++p) {
      const float ox = (float)offp[l * 8 + p * 2], oy = (float)offp[l * 8 + p * 2 + 1];
      const float a = aw[l * 4 + p] * sinv;
      const float x = (rx + ox / fW) * fW - 0.5f;
      const float y = (ry + oy / fW) * fW - 0.5f;
      const float x0f = floorf(x), y0f = floorf(y);
      const float wx = x - x0f, wy = y - y0f;
      const int x0 = (int)x0f, y0 = (int)y0f;
      const int x1 = x0 + 1, y1 = y0 + 1;
      const bool xv0 = (x0 >= 0) & (x0 < Wl);
      const bool xv1 = (x1 >= 0) & (x1 < Wl);
      const bool yv0 = (y0 >= 0) & (y0 < Wl);
      const bool yv1 = (y1 >= 0) & (y1 < Wl);
      const int cx0 = min(max(x0, 0), Wl - 1), cx1 = min(max(x1, 0), Wl - 1);
      const int cy0 = min(max(y0, 0), Wl - 1), cy1 = min(max(y1, 0), Wl - 1);
      const float w00 = (xv0 && yv0) ? (1.f - wx) * (1.f - wy) * a : 0.f;
      const float w01 = (xv1 && yv0) ? wx * (1.f - wy) * a : 0.f;
      const float w10 = (xv0 && yv1) ? (1.f - wx) * wy * a : 0.f;
      const float w11 = (xv1 && yv1) ? wx * wy * a : 0.f;
      const bh8 g00 = *(const bh8*)(vb + (cy0 * Wl + cx0) * 256);
      const bh8 g01 = *(const bh8*)(vb + (cy0 * Wl + cx1) * 256);
      const bh8 g10 = *(const bh8*)(vb + (cy1 * Wl + cx0) * 256);
      const bh8 g11 = *(const bh8*)(vb + (cy1 * Wl + cx1) * 256);
#pragma unroll
      for (int e = 0; e < 8; ++e)
        acc[e] = fmaf(w00, (float)g00[e], fmaf(w01, (float)g01[e],
                 fmaf(w10, (float)g10[e], fmaf(w11, (float)g11[e], acc[e]))));
    }
  }
  bh8 o;
#pragma unroll
  for (int e = 0; e < 8; ++e) o[e] = (bhalf)acc[e];
  *(bh8*)(out + (long long)bi * 256 + c0) = o;
}

// =====================================================================
// src[b][startRow+hw][c] -> out[b][c][hw]
// =====================================================================
__global__ void transpose_out_kernel(const float* __restrict__ src, float* __restrict__ out,
    int HW, int startRow)
{
  __shared__ float tile[32][33];
  int b = blockIdx.z;
  int w0 = blockIdx.x * 32, c0 = blockIdx.y * 32;
#pragma unroll
  for (int j = 0; j < 4; ++j) {
    int wl = threadIdx.y + 8 * j;
    tile[wl][threadIdx.x] = src[((long long)b * NLEN + startRow + w0 + wl) * 256 + c0 + threadIdx.x];
  }
  __syncthreads();
#pragma unroll
  for (int j = 0; j < 4; ++j) {
    int cl = threadIdx.y + 8 * j;
    out[((long long)b * 256 + c0 + cl) * HW + w0 + threadIdx.x] = tile[threadIdx.x][cl];
  }
}

// =====================================================================
// latb = GN(lat) + upsample2x(src lvl2), zero-padded layout
// =====================================================================
__global__ void lat_finish_rm_kernel(const bhalf* __restrict__ lat, const float* __restrict__ stats,
    const float* __restrict__ gs, const float* __restrict__ gb,
    const float* __restrict__ src, bhalf* __restrict__ latb)
{
  long long idx = (long long)blockIdx.x * 256 + threadIdx.x;
  int c = threadIdx.x & 255;
  long long row = idx >> 8;
  int b = (int)(row / 36864);
  int p = (int)(row - (long long)b * 36864);
  int y = p / 192, x = p % 192;
  int g = c >> 3;
  float v = (float)lat[idx];
  v = (v - stats[(b * 32 + g) * 2]) * stats[(b * 32 + g) * 2 + 1] * gs[c] + gb[c];
  float ys = fmaxf(y * 0.5f - 0.25f, 0.f);
  float xs = fmaxf(x * 0.5f - 0.25f, 0.f);
  int y0 = (int)ys; float wy = ys - (float)y0; int y1 = min(y0 + 1, 95);
  int x0 = (int)xs; float wx = xs - (float)x0; int x1 = min(x0 + 1, 95);
  const float* sp = src + ((long long)b * NLEN + 2880) * 256 + c;
  float r0 = sp[(long long)(y0 * 96 + x0) * 256] * (1.f - wx) + sp[(long long)(y0 * 96 + x1) * 256] * wx;
  float r1 = sp[(long long)(y1 * 96 + x0) * 256] * (1.f - wx) + sp[(long long)(y1 * 96 + x1) * 256] * wx;
  latb[((long long)b * 37636 + (long long)(y + 1) * 194 + (x + 1)) * 256 + c]
      = (bhalf)(v + r0 * (1.f - wy) + r1 * wy);
}

// =====================================================================
// Final GN+ReLU+transpose: convC bf16 [b][hw][c] -> Y fp32 [b][c][hw]
// =====================================================================
__global__ void gn_relu_tr_kernel(const bhalf* __restrict__ convC, const float* __restrict__ stats,
    const float* __restrict__ gs, const float* __restrict__ gb, float* __restrict__ Y)
{
  __shared__ float tile[32][33];
  int b = blockIdx.z;
  int hw0 = blockIdx.x * 32, c0 = blockIdx.y * 32;
#pragma unroll
  for (int j = 0; j < 4; ++j) {
    int hwl = threadIdx.y + 8 * j;
    int c = c0 + threadIdx.x;
    int g = c >> 3;
    float v = (float)convC[((long long)b * 36864 + hw0 + hwl) * 256 + c];
    v = (v - stats[(b * 32 + g) * 2]) * stats[(b * 32 + g) * 2 + 1] * gs[c] + gb[c];
    tile[hwl][threadIdx.x] = fmaxf(v, 0.f);
  }
  __syncthreads();
#pragma unroll
  for (int j = 0; j < 4; ++j) {
    int cl = threadIdx.y + 8 * j;
    Y[((long long)b * 256 + c0 + cl) * 36864 + hw0 + threadIdx.x] = tile[threadIdx.x][cl];
  }
}

// =====================================================================
extern "C" void kernel_launch(void* const* d_in, const int* in_sizes, int n_in,
                              void* d_out, int out_size, void* d_ws, size_t ws_size,
                              hipStream_t stream)
{
  const float* res2 = (const float*)d_in[0];
  const float* res3 = (const float*)d_in[1];
  const float* res4 = (const float*)d_in[2];
  const float* res5 = (const float*)d_in[3];
  const float* pw[3]  = {(const float*)d_in[4],  (const float*)d_in[8],  (const float*)d_in[12]};
  const float* pb[3]  = {(const float*)d_in[5],  (const float*)d_in[9],  (const float*)d_in[13]};
  const float* gss[3] = {(const float*)d_in[6],  (const float*)d_in[10], (const float*)d_in[14]};
  const float* gbb[3] = {(const float*)d_in[7],  (const float*)d_in[11], (const float*)d_in[15]};
  const float* level_embed = (const float*)d_in[16];
  const float* off_w = (const float*)d_in[17];
  const float* off_b = (const float*)d_in[18];
  const float* aw_w  = (const float*)d_in[19];
  const float* aw_b  = (const float*)d_in[20];
  const float* val_w = (const float*)d_in[21];
  const float* val_b = (const float*)d_in[22];
  const float* out_w = (const float*)d_in[23];
  const float* out_b = (const float*)d_in[24];
  const float* ln1_s = (const float*)d_in[25];
  const float* ln1_b = (const float*)d_in[26];
  const float* ffn1_w = (const float*)d_in[27];
  const float* ffn1_b = (const float*)d_in[28];
  const float* ffn2_w = (const float*)d_in[29];
  const float* ffn2_b = (const float*)d_in[30];
  const float* ln2_s = (const float*)d_in[31];
  const float* ln2_b = (const float*)d_in[32];
  const float* lat_w = (const float*)d_in[33];
  const float* lat_gs = (const float*)d_in[34];
  const float* lat_gb = (const float*)d_in[35];
  const float* fpn_w = (const float*)d_in[36];
  const float* fpn_gs = (const float*)d_in[37];
  const float* fpn_gb = (const float*)d_in[38];

  char* W = (char*)d_ws;
  float* src   = (float*)(W + 0);
  float* pos   = (float*)(W + 24772608LL);
  float* tmp   = (float*)(W + 37158912LL);
  bhalf* srcb  = (bhalf*)(W + 61931520LL);
  bhalf* wreg  = (bhalf*)(W + 74317824LL);
  float* stats = (float*)(W + 86212608LL);
  float* part  = (float*)(W + 86213120LL);
  float* offaw_b = (float*)(W + 86278656LL);
  char*  U     = W + 86286848LL;

  bhalf* valT   = wreg + 0;
  bhalf* offawT = wreg + 393216;
  bhalf* outT   = wreg + 835584;
  bhalf* f1T    = wreg + 1228800;
  bhalf* f2T    = wreg + 2801664;
  bhalf* pwb5   = wreg + 4374528;
  bhalf* pwb4   = wreg + 4898816;
  bhalf* pwb3   = wreg + 5160960;
  bhalf* latwb  = wreg + 5292032;
  bhalf* fpnT   = wreg + 5357568;

  bhalf* qb      = (bhalf*)(U + 0);
  bhalf* valueb  = (bhalf*)(U + 12386304LL);
  bhalf* sampb   = (bhalf*)(U + 24772608LL);
  bhalf* offbuf  = (bhalf*)(U + 37158912LL);   // [M][288] bf16 = 13.9 MB
  bhalf* hbuf    = (bhalf*)(U + 65028096LL);
  bhalf* featT   = (bhalf*)(U + 24772608LL);   // projection-phase only
  bhalf* res2T   = (bhalf*)(U + 0);
  bhalf* latbf   = (bhalf*)(U + 37748736LL);
  bhalf* latb    = (bhalf*)(U + 75497472LL);

  float* Yout = (float*)d_out;
  float* out0 = Yout + 18874368LL;
  float* out1 = Yout + 19169280LL;
  float* out2 = Yout + 20348928LL;

  const int M = BB * NLEN;  // 24192

  // ---- weight prep ----
  twcvt_kernel<<<dim3(8, 8, 6), dim3(32, 8), 0, stream>>>(val_w, valT, 256, 256, 65536LL);
  twcvt_kernel<<<dim3(6, 8, 6), dim3(32, 8), 0, stream>>>(off_w, offawT, 256, 192, 73728LL);
  twcvt_kernel<<<dim3(3, 8, 6), dim3(32, 8), 0, stream>>>(aw_w, offawT + 192 * 256, 256, 96, 73728LL);
  twcvt_kernel<<<dim3(8, 8, 6), dim3(32, 8), 0, stream>>>(out_w, outT, 256, 256, 65536LL);
  twcvt_kernel<<<dim3(32, 8, 6), dim3(32, 8), 0, stream>>>(ffn1_w, f1T, 256, 1024, 262144LL);
  twcvt_kernel<<<dim3(8, 32, 6), dim3(32, 8), 0, stream>>>(ffn2_w, f2T, 1024, 256, 262144LL);
  biascat_kernel<<<dim3(6), dim3(288), 0, stream>>>(off_b, aw_b, offaw_b);
  cvt_kernel<<<dim3(2048), dim3(256), 0, stream>>>(pw[0], pwb5, 524288);
  cvt_kernel<<<dim3(1024), dim3(256), 0, stream>>>(pw[1], pwb4, 262144);
  cvt_kernel<<<dim3(512),  dim3(256), 0, stream>>>(pw[2], pwb3, 131072);
  cvt_kernel<<<dim3(256),  dim3(256), 0, stream>>>(lat_w, latwb, 65536);
  fpnw_kernel<<<dim3(2304), dim3(256), 0, stream>>>(fpn_w, fpnT);

  // ---- positional embedding ----
  pos_kernel<<<dim3(NLEN), dim3(256), 0, stream>>>(pos, level_embed);

  // ---- input projections + GN -> src/srcb/qb ----
  const float* feats[3] = {res5, res4, res3};
  const bhalf* pwbs[3] = {pwb5, pwb4, pwb3};
  const int cins[3] = {2048, 1024, 512};
  const int HWs[3] = {576, 2304, 9216};
  const int startsHost[3] = {0, 576, 2880};
  const int nchs[3] = {16, 64, 128};
  for (int lvl = 0; lvl < 3; ++lvl) {
    int HW = HWs[lvl], cin = cins[lvl], nch = nchs[lvl];
    tfeat_kernel<<<dim3(HW / 32, cin / 32, BB), dim3(32, 8), 0, stream>>>(feats[lvl], featT, cin, HW);
    bgemm_kernel<<<dim3(2, (HW + 127) / 128, BB), dim3(256), 0, stream>>>(
        featT, pwbs[lvl], pb[lvl], tmp, HW, 256, cin,
        (long long)HW * cin, 0LL, (long long)HW * 256, 0, 0);
    gn_part_kernel<<<dim3(nch, BB), dim3(256), 0, stream>>>(tmp, part, HW, 0, nch);
    gn_fin_kernel<<<dim3(64), dim3(64), 0, stream>>>(part, stats, nch, HW);
    gn_apply_rm_kernel<<<dim3(BB * HW), dim3(256), 0, stream>>>(
        tmp, stats, gss[lvl], gbb[lvl], src, srcb, qb, pos, HW, startsHost[lvl]);
  }

  // ---- 6 encoder layers ----
  for (int l = 0; l < 6; ++l) {
    bgemm_kernel<<<dim3(2, M / 128, 1), dim3(256), 0, stream>>>(
        srcb, valT + (long long)l * 65536, val_b + l * 256, valueb,
        M, 256, 256, 0LL, 0LL, 0LL, 1, 0);
    bgemm_kernel<<<dim3(3, M / 128, 1), dim3(256), 0, stream>>>(
        qb, offawT + (long long)l * 73728, offaw_b + l * 288, offbuf,
        M, 288, 256, 0LL, 0LL, 0LL, 1, 0);
    deform_kernel<<<dim3(M / 8), dim3(256), 0, stream>>>(valueb, offbuf, sampb);
    bgemm_ln_kernel<<<dim3(M / 64), dim3(256), 0, stream>>>(
        sampb, outT + (long long)l * 65536, out_b + l * 256,
        src, srcb, nullptr, pos, ln1_s + l * 256, ln1_b + l * 256, M, 256);
    bgemm_kernel<<<dim3(8, M / 128, 1), dim3(256), 0, stream>>>(
        srcb, f1T + (long long)l * 262144, ffn1_b + l * 1024, hbuf,
        M, 1024, 256, 0LL, 0LL, 0LL, 1, 1);
    bgemm_ln_kernel<<<dim3(M / 64), dim3(256), 0, stream>>>(
        hbuf, f2T + (long long)l * 262144, ffn2_b + l * 256,
        src, srcb, qb, pos, ln2_s + l * 256, ln2_b + l * 256, M, 1024);
  }

  // ---- output transposes ----
  float* outsPtr[3] = {out0, out1, out2};
  for (int lvl = 0; lvl < 3; ++lvl) {
    transpose_out_kernel<<<dim3(HWs[lvl] / 32, 8, BB), dim3(32, 8), 0, stream>>>(
        src, outsPtr[lvl], HWs[lvl], startsHost[lvl]);
  }

  // ---- FPN ----
  tfeat_kernel<<<dim3(1152, 8, BB), dim3(32, 8), 0, stream>>>(res2, res2T, 256, 36864);
  bgemm_kernel<<<dim3(2, 288, BB), dim3(256), 0, stream>>>(
      res2T, latwb, nullptr, latbf, 36864, 256, 256,
      36864LL * 256, 0LL, 36864LL * 256, 1, 0);
  gn_part_kernel<<<dim3(128, BB), dim3(256), 0, stream>>>(latbf, part, 36864, 1, 128);
  gn_fin_kernel<<<dim3(64), dim3(64), 0, stream>>>(part, stats, 128, 36864);
  border_zero_kernel<<<dim3((BB * 4 * 194 + 255) / 256), dim3(256), 0, stream>>>(latb);
  lat_finish_rm_kernel<<<dim3(73728), dim3(256), 0, stream>>>(latbf, stats, lat_gs, lat_gb, src, latb);
  bgemm_conv_kernel<<<dim3(2, 288, BB), dim3(256), 0, stream>>>(latb, fpnT, latbf);
  gn_part_kernel<<<dim3(128, BB), dim3(256), 0, stream>>>(latbf, part, 36864, 1, 128);
  gn_fin_kernel<<<dim3(64), dim3(64), 0, stream>>>(part, stats, 128, 36864);
  gn_relu_tr_kernel<<<dim3(1152, 8, BB), dim3(32, 8), 0, stream>>>(latbf, stats, fpn_gs, fpn_gb, Yout);
}

// Round 13
// 1581.852 us; speedup vs baseline: 1.1644x; 1.1198x over previous
//
#include <hip/hip_runtime.h>
#include <math.h>

#define NLEN 12096
#define BB 2

typedef __bf16 bhalf;
typedef bhalf bh8 __attribute__((ext_vector_type(8)));
typedef bhalf bh4 __attribute__((ext_vector_type(4)));
typedef float f32x4 __attribute__((ext_vector_type(4)));

// LDS 16B-slot swizzle (verified round 8: bank conflicts -> 0). BK=32.
// Note swz(row+32k*4)==swz(row): unified A|B row offsets preserve banking.
__device__ __forceinline__ int swz(int row) { return (row >> 1) & 3; }

// Bijective XCD-chunk swizzle (T1, m204).
__device__ __forceinline__ int xcd_swz(int id, int nwg) {
  int q = nwg >> 3, r = nwg & 7;
  int xcd = id & 7, pos = id >> 3;
  int base = (xcd < r) ? xcd * (q + 1) : r * (q + 1) + (xcd - r) * q;
  return base + pos;
}

#define GLOAD_LDS16(g, l) \
  __builtin_amdgcn_global_load_lds( \
      (const __attribute__((address_space(1))) unsigned int*)(g), \
      (__attribute__((address_space(3))) unsigned int*)(l), 16, 0, 0)

// =====================================================================
// bf16 MFMA GEMM, tile 128 x (16*BNF), BK=32, 4 waves (2x2).
// C[M,N] = A[M,K] @ Bt[N,K]^T (+bias[n]) (+relu). gload_lds staging,
// unified LDS: rows [0,128)=A, [128,128+BN)=Bt.
// =====================================================================
template<int BNF>
__global__ __launch_bounds__(256) void bgemm_t_kernel(
    const bhalf* __restrict__ A, const bhalf* __restrict__ Bt,
    const float* __restrict__ bias, void* __restrict__ Cout,
    int M, int N, int K, long long sA, long long sB, long long sC,
    int outBf16, int relu)
{
  constexpr int BN = BNF * 16;
  constexpr int ROWS = 128 + BN;
  constexpr int UNITS = ROWS * 4;            // 16B units per k-step
  constexpr int ITERS = (UNITS + 255) / 256;
  constexpr int NFR = BNF / 2;               // n-frags per wave
  const int gx = gridDim.x, gy = gridDim.y;
  const int nwg = gx * gy * gridDim.z;
  int flat = (blockIdx.z * gy + blockIdx.y) * gx + blockIdx.x;
  int logical = xcd_swz(flat, nwg);
  const int bz = logical / (gx * gy);
  int rem = logical - bz * gx * gy;
  const int by = rem / gx;
  const int bx = rem - by * gx;

  A += bz * sA; Bt += bz * sB;
  const int m0 = by * 128, n0 = bx * BN;
  __shared__ __align__(16) bhalf Ls[ROWS * 32];
  const int t = threadIdx.x;
  const int lane = t & 63;
  const int w = t >> 6;
  const int wbase = t & 192;
  const int wm = (w >> 1) * 64, wn = (w & 1) * (BN / 2);
  const int fr = lane & 15, fg = lane >> 4;
  f32x4 acc[4][NFR] = {};
  for (int k0 = 0; k0 < K; k0 += 32) {
#pragma unroll
    for (int j = 0; j < ITERS; ++j) {
      int u = t + j * 256;
      if (UNITS % 256 == 0 || u < UNITS) {
        int row = u >> 2, up = u & 3;
        int kcg = ((up ^ swz(row)) * 8);
        const bhalf* gsrc;
        if (row < 128) {
          int m = m0 + row; m = (m < M) ? m : (M - 1);
          gsrc = A + (long long)m * K + k0 + kcg;
        } else {
          int n = n0 + row - 128; n = (n < N) ? n : (N - 1);
          gsrc = Bt + (long long)n * K + k0 + kcg;
        }
        GLOAD_LDS16(gsrc, Ls + (long long)(wbase + j * 256) * 8);
      }
    }
    __syncthreads();
    bh8 af[4], bf[NFR];
#pragma unroll
    for (int mi = 0; mi < 4; ++mi) {
      int r = wm + mi * 16 + fr;
      af[mi] = *(const bh8*)(Ls + r * 32 + ((fg ^ swz(r)) * 8));
    }
#pragma unroll
    for (int ni = 0; ni < NFR; ++ni) {
      int r = 128 + wn + ni * 16 + fr;
      bf[ni] = *(const bh8*)(Ls + r * 32 + ((fg ^ swz(r)) * 8));
    }
#pragma unroll
    for (int mi = 0; mi < 4; ++mi)
#pragma unroll
      for (int ni = 0; ni < NFR; ++ni)
        acc[mi][ni] = __builtin_amdgcn_mfma_f32_16x16x32_bf16(af[mi], bf[ni], acc[mi][ni], 0, 0, 0);
    __syncthreads();
  }
  float* Cf = (float*)Cout + bz * sC;
  bhalf* Cb = (bhalf*)Cout + bz * sC;
#pragma unroll
  for (int mi = 0; mi < 4; ++mi) {
#pragma unroll
    for (int r = 0; r < 4; ++r) {
      int m = m0 + wm + mi * 16 + fg * 4 + r;
      if (m >= M) continue;
#pragma unroll
      for (int ni = 0; ni < NFR; ++ni) {
        int n = n0 + wn + ni * 16 + fr;
        if (n >= N) continue;
        float v = acc[mi][ni][r];
        if (bias) v += bias[n];
        if (relu) v = fmaxf(v, 0.f);
        if (outBf16) Cb[(long long)m * N + n] = (bhalf)v;
        else         Cf[(long long)m * N + n] = v;
      }
    }
  }
}

// =====================================================================
// Fused GEMM + bias + residual + LayerNorm. Tile 32x256, BK=32,
// 4 waves (2 row-halves of 16 x 2 col-halves of 128). 756 blocks.
// =====================================================================
__global__ __launch_bounds__(256) void bgemm_ln_kernel(
    const bhalf* __restrict__ A, const bhalf* __restrict__ Bt,
    const float* __restrict__ bias,
    float* __restrict__ src, bhalf* __restrict__ srcb,
    bhalf* __restrict__ qbOut, const float* __restrict__ pos,
    const float* __restrict__ ls, const float* __restrict__ lb,
    int M, int K)
{
  const int nwg = gridDim.x;
  const int bid = xcd_swz(blockIdx.x, nwg);
  const int m0 = bid * 32;
  // rows [0,32)=A, [32,288)=Bt(all 256 weight rows): 18 KB
  __shared__ __align__(16) bhalf Ls[288 * 32];
  __shared__ float shS[32][2], shQ[32][2];
  const int t = threadIdx.x;
  const int lane = t & 63;
  const int w = t >> 6;
  const int wbase = t & 192;
  const int wm = (w >> 1) * 16, wn = (w & 1) * 128;
  const int fr = lane & 15, fg = lane >> 4;
  f32x4 acc[8] = {};
  for (int k0 = 0; k0 < K; k0 += 32) {
#pragma unroll
    for (int j = 0; j < 5; ++j) {
      int u = t + j * 256;
      if (u < 1152) {
        int row = u >> 2, up = u & 3;
        int kcg = ((up ^ swz(row)) * 8);
        const bhalf* gsrc = (row < 32)
            ? (A + (long long)(m0 + row) * K + k0 + kcg)
            : (Bt + (long long)(row - 32) * K + k0 + kcg);
        GLOAD_LDS16(gsrc, Ls + (long long)(wbase + j * 256) * 8);
      }
    }
    __syncthreads();
    bh8 af, bf[8];
    {
      int r = wm + fr;
      af = *(const bh8*)(Ls + r * 32 + ((fg ^ swz(r)) * 8));
    }
#pragma unroll
    for (int ni = 0; ni < 8; ++ni) {
      int r = 32 + wn + ni * 16 + fr;
      bf[ni] = *(const bh8*)(Ls + r * 32 + ((fg ^ swz(r)) * 8));
    }
#pragma unroll
    for (int ni = 0; ni < 8; ++ni)
      acc[ni] = __builtin_amdgcn_mfma_f32_16x16x32_bf16(af, bf[ni], acc[ni], 0, 0, 0);
    __syncthreads();
  }
  // epilogue: v = acc + bias + src; per-row LN stats
#pragma unroll
  for (int r = 0; r < 4; ++r) {
    int rt = wm + fg * 4 + r;
    long long gm = m0 + rt;
    float s = 0.f, q = 0.f;
#pragma unroll
    for (int ni = 0; ni < 8; ++ni) {
      int col = wn + ni * 16 + fr;
      float v = acc[ni][r] + bias[col] + src[gm * 256 + col];
      acc[ni][r] = v;
      s += v; q = fmaf(v, v, q);
    }
#pragma unroll
    for (int o = 1; o < 16; o <<= 1) { s += __shfl_xor(s, o); q += __shfl_xor(q, o); }
    if (fr == 0) { shS[rt][w & 1] = s; shQ[rt][w & 1] = q; }
  }
  __syncthreads();
#pragma unroll
  for (int r = 0; r < 4; ++r) {
    int rt = wm + fg * 4 + r;
    long long gm = m0 + rt;
    float S = shS[rt][0] + shS[rt][1];
    float Q = shQ[rt][0] + shQ[rt][1];
    float mean = S * (1.f / 256.f);
    float var = Q * (1.f / 256.f) - mean * mean;
    float rstd = rsqrtf(var + 1e-5f);
    int prow = (int)(gm % NLEN);
#pragma unroll
    for (int ni = 0; ni < 8; ++ni) {
      int col = wn + ni * 16 + fr;
      float y = (acc[ni][r] - mean) * rstd * ls[col] + lb[col];
      src[gm * 256 + col] = y;
      srcb[gm * 256 + col] = (bhalf)y;
      if (qbOut) qbOut[gm * 256 + col] = (bhalf)(y + pos[(long long)prow * 256 + col]);
    }
  }
}

// =====================================================================
// Implicit-GEMM 3x3 conv, BK=32, ci_block-major / tap-inner.
// =====================================================================
__global__ __launch_bounds__(256) void bgemm_conv_kernel(
    const bhalf* __restrict__ Ab, const bhalf* __restrict__ Bt,
    bhalf* __restrict__ Cout)
{
  const int gx = gridDim.x, gy = gridDim.y;
  const int nwg = gx * gy * gridDim.z;
  int flat = (blockIdx.z * gy + blockIdx.y) * gx + blockIdx.x;
  int logical = xcd_swz(flat, nwg);
  const int bz = logical / (gx * gy);
  int rem = logical - bz * gx * gy;
  const int by = rem / gx;
  const int bx = rem - by * gx;

  const bhalf* Apad = Ab + (long long)bz * 37636 * 256;
  const int m0 = by * 128, n0 = bx * 128;
  __shared__ __align__(16) bhalf As[128 * 32];
  __shared__ __align__(16) bhalf Bs[128 * 32];
  const int t = threadIdx.x;
  const int lane = t & 63;
  const int w = t >> 6;
  const int wbase = t & 192;
  const int wm = (w >> 1) * 64, wn = (w & 1) * 64;
  const int fr = lane & 15, fg = lane >> 4;
  int rowA[2], py[2], px[2], kcg[2];
#pragma unroll
  for (int j = 0; j < 2; ++j) {
    int id = t + j * 256;
    rowA[j] = id >> 2;
    kcg[j] = (((id & 3) ^ swz(rowA[j])) * 8);
    int m = m0 + rowA[j];
    py[j] = m / 192; px[j] = m % 192;
  }
  f32x4 acc[4][4] = {};
  for (int s = 0; s < 72; ++s) {
    const int cib = s / 9, tap = s % 9;
    const int ty = tap / 3, tx = tap % 3;
#pragma unroll
    for (int j = 0; j < 2; ++j) {
      GLOAD_LDS16(Apad + ((long long)(py[j] + ty) * 194 + px[j] + tx) * 256 + cib * 32 + kcg[j],
                  As + (wbase + j * 256) * 8);
      GLOAD_LDS16(Bt + (long long)(n0 + rowA[j]) * 2304 + s * 32 + kcg[j],
                  Bs + (wbase + j * 256) * 8);
    }
    __syncthreads();
    bh8 af[4], bf[4];
#pragma unroll
    for (int mi = 0; mi < 4; ++mi) {
      int r = wm + mi * 16 + fr;
      af[mi] = *(const bh8*)(As + r * 32 + ((fg ^ swz(r)) * 8));
    }
#pragma unroll
    for (int ni = 0; ni < 4; ++ni) {
      int r = wn + ni * 16 + fr;
      bf[ni] = *(const bh8*)(Bs + r * 32 + ((fg ^ swz(r)) * 8));
    }
#pragma unroll
    for (int mi = 0; mi < 4; ++mi)
#pragma unroll
      for (int ni = 0; ni < 4; ++ni)
        acc[mi][ni] = __builtin_amdgcn_mfma_f32_16x16x32_bf16(af[mi], bf[ni], acc[mi][ni], 0, 0, 0);
    __syncthreads();
  }
  bhalf* Cb = Cout + (long long)bz * 36864 * 256;
#pragma unroll
  for (int mi = 0; mi < 4; ++mi)
#pragma unroll
    for (int r = 0; r < 4; ++r) {
      int m = m0 + wm + mi * 16 + fg * 4 + r;
#pragma unroll
      for (int ni = 0; ni < 4; ++ni) {
        int n = n0 + wn + ni * 16 + fr;
        Cb[(long long)m * 256 + n] = (bhalf)acc[mi][ni][r];
      }
    }
}

// =====================================================================
// Fused weight transpose+convert: all 6 [z][Kd][Nd]->[z][Nd][Kd] groups
// in ONE launch; flattened 32x32 tiles, block (32,8).
// =====================================================================
__global__ void wprep_t_kernel(
    const float* __restrict__ s0, const float* __restrict__ s1,
    const float* __restrict__ s2, const float* __restrict__ s3,
    const float* __restrict__ s4, const float* __restrict__ s5,
    bhalf* __restrict__ d0, bhalf* __restrict__ d1, bhalf* __restrict__ d2,
    bhalf* __restrict__ d3, bhalf* __restrict__ d4, bhalf* __restrict__ d5)
{
  // seg: Kd, Nd, zdst, ntiles(cum)
  const int KdA[6]  = {256, 256, 256, 256, 256, 1024};
  const int NdA[6]  = {256, 192, 96, 256, 1024, 256};
  const long long zdA[6] = {65536, 73728, 73728, 65536, 262144, 262144};
  const int cum[6]  = {384, 672, 816, 1200, 2736, 4272};
  int blk = blockIdx.x;
  int seg = 0;
#pragma unroll
  for (int i = 0; i < 6; ++i) if (blk >= cum[i]) seg = i + 1;
  int base = (seg == 0) ? 0 : cum[seg - 1];
  int idx = blk - base;
  const float* Wsrc = (seg == 0) ? s0 : (seg == 1) ? s1 : (seg == 2) ? s2
                    : (seg == 3) ? s3 : (seg == 4) ? s4 : s5;
  bhalf* out = (seg == 0) ? d0 : (seg == 1) ? d1 : (seg == 2) ? d2
             : (seg == 3) ? d3 : (seg == 4) ? d4 : d5;
  int Kd = KdA[seg], Nd = NdA[seg];
  int nx = Nd / 32, ny = Kd / 32;
  int z = idx / (nx * ny);
  int r = idx - z * nx * ny;
  int ky = r / nx, nxi = r - ky * nx;
  __shared__ float tile[32][33];
  long long zi = (long long)z * Kd * Nd;
  long long zo = (long long)z * zdA[seg];
  int n0 = nxi * 32, k0 = ky * 32;
#pragma unroll
  for (int j = 0; j < 4; ++j) {
    int kk = threadIdx.y + 8 * j;
    tile[kk][threadIdx.x] = Wsrc[zi + (long long)(k0 + kk) * Nd + n0 + threadIdx.x];
  }
  __syncthreads();
#pragma unroll
  for (int j = 0; j < 4; ++j) {
    int nn = threadIdx.y + 8 * j;
    out[zo + (long long)(n0 + nn) * Kd + k0 + threadIdx.x] = (bhalf)tile[threadIdx.x][nn];
  }
}

// =====================================================================
// Fused misc weight prep: fpnw + 4 cvts + biascat in one launch.
// ranges: [0,2304) fpnw | [2304,4352) pw5 | [4352,5376) pw4 |
// [5376,5888) pw3 | [5888,6144) latw | [6144,6151) biascat
// =====================================================================
__global__ void wprep_m_kernel(
    const float* __restrict__ fpn_w, bhalf* __restrict__ fpnT,
    const float* __restrict__ pw5, bhalf* __restrict__ pwb5,
    const float* __restrict__ pw4, bhalf* __restrict__ pwb4,
    const float* __restrict__ pw3, bhalf* __restrict__ pwb3,
    const float* __restrict__ lat_w, bhalf* __restrict__ latwb,
    const float* __restrict__ ob, const float* __restrict__ ab,
    float* __restrict__ offaw_b)
{
  int blk = blockIdx.x, t = threadIdx.x;
  if (blk < 2304) {
    int o = blk * 256 + t;
    int co = o / 2304, r = o % 2304;
    int cib = r / 288, rr = r % 288, tap = rr >> 5, cil = rr & 31;
    int ci = cib * 32 + cil;
    fpnT[o] = (bhalf)fpn_w[(co * 256 + ci) * 9 + tap];
  } else if (blk < 4352) {
    int i = (blk - 2304) * 256 + t; pwb5[i] = (bhalf)pw5[i];
  } else if (blk < 5376) {
    int i = (blk - 4352) * 256 + t; pwb4[i] = (bhalf)pw4[i];
  } else if (blk < 5888) {
    int i = (blk - 5376) * 256 + t; pwb3[i] = (bhalf)pw3[i];
  } else if (blk < 6144) {
    int i = (blk - 5888) * 256 + t; latwb[i] = (bhalf)lat_w[i];
  } else {
    int i = (blk - 6144) * 256 + t;
    if (i < 6 * 288) {
      int l = i / 288, c = i % 288;
      offaw_b[i] = (c < 192) ? ob[l * 192 + c] : ab[l * 96 + c - 192];
    }
  }
}

__global__ void tfeat_kernel(const float* __restrict__ Fsrc, bhalf* __restrict__ out,
                             int Ci, int HW)
{
  __shared__ float tile[32][33];
  long long zo = (long long)blockIdx.z * Ci * HW;
  int hw0 = blockIdx.x * 32, c0 = blockIdx.y * 32;
#pragma unroll
  for (int j = 0; j < 4; ++j) {
    int cc = threadIdx.y + 8 * j;
    tile[cc][threadIdx.x] = Fsrc[zo + (long long)(c0 + cc) * HW + hw0 + threadIdx.x];
  }
  __syncthreads();
#pragma unroll
  for (int j = 0; j < 4; ++j) {
    int hh = threadIdx.y + 8 * j;
    out[zo + (long long)(hw0 + hh) * Ci + c0 + threadIdx.x] = (bhalf)tile[threadIdx.x][hh];
  }
}

// zero 1-px border of padded [B][194*194][256] bf16 buffer
__global__ void border_zero_kernel(bhalf* __restrict__ latb)
{
  int idx = blockIdx.x * 256 + threadIdx.x;
  int total = BB * 4 * 194;
  if (idx >= total) return;
  int b = idx / (4 * 194);
  int r = idx - b * 4 * 194;
  int strip = r / 194, p = r % 194;
  int y, x;
  if (strip == 0)      { y = 0;   x = p; }
  else if (strip == 1) { y = 193; x = p; }
  else if (strip == 2) { y = p;   x = 0; }
  else                 { y = p;   x = 193; }
  uint4* dst = (uint4*)(latb + ((long long)b * 37636 + (long long)y * 194 + x) * 256);
#pragma unroll
  for (int j = 0; j < 32; ++j) dst[j] = make_uint4(0u, 0u, 0u, 0u);
}

// =====================================================================
// Sine positional embedding + level embed
// =====================================================================
__global__ void pos_kernel(float* __restrict__ pos, const float* __restrict__ level_embed)
{
  int i = blockIdx.x, c = threadIdx.x;
  int lvl, Wq, loc;
  if (i < 576)       { lvl = 0; Wq = 24; loc = i; }
  else if (i < 2880) { lvl = 1; Wq = 48; loc = i - 576; }
  else               { lvl = 2; Wq = 96; loc = i - 2880; }
  int h = loc / Wq, wcol = loc % Wq;
  int cc = c & 127;
  float coord = (c < 128) ? (float)(h + 1) : (float)(wcol + 1);
  float denom = (float)Wq + 1e-6f;
  float v = coord / denom * 6.28318530717958647692f;
  float tp = powf(10000.0f, (float)(cc & ~1) * (1.0f / 128.0f));
  float ang = v / tp;
  float val = (cc & 1) ? cosf(ang) : sinf(ang);
  pos[(long long)i * 256 + c] = val + level_embed[lvl * 256 + c];
}

// =====================================================================
// GN stats, two-pass, coalesced.
// =====================================================================
__global__ __launch_bounds__(256) void gn_part_kernel(const void* __restrict__ X,
    float* __restrict__ part, int HW, int isBf16, int nch)
{
  const int b = blockIdx.y, ch = blockIdx.x;
  const int rows = (HW + nch - 1) / nch;
  const int r0 = ch * rows;
  const int r1 = min(r0 + rows, HW);
  const int cg = threadIdx.x & 31;
  const int ro = threadIdx.x >> 5;
  float s = 0.f, s2 = 0.f;
  if (isBf16) {
    const bhalf* p = (const bhalf*)X + (long long)b * HW * 256 + cg * 8;
    for (int r = r0 + ro; r < r1; r += 8) {
      bh8 v = *(const bh8*)(p + (long long)r * 256);
#pragma unroll
      for (int j = 0; j < 8; ++j) { float f = (float)v[j]; s += f; s2 = fmaf(f, f, s2); }
    }
  } else {
    const float* p = (const float*)X + (long long)b * HW * 256 + cg * 8;
    for (int r = r0 + ro; r < r1; r += 8) {
      f32x4 v0 = *(const f32x4*)(p + (long long)r * 256);
      f32x4 v1 = *(const f32x4*)(p + (long long)r * 256 + 4);
#pragma unroll
      for (int j = 0; j < 4; ++j) { s += v0[j]; s2 = fmaf(v0[j], v0[j], s2); }
#pragma unroll
      for (int j = 0; j < 4; ++j) { s += v1[j]; s2 = fmaf(v1[j], v1[j], s2); }
    }
  }
  __shared__ float sh[2][8][32];
  sh[0][ro][cg] = s; sh[1][ro][cg] = s2;
  __syncthreads();
  if (threadIdx.x < 32) {
    float S = 0.f, S2 = 0.f;
#pragma unroll
    for (int k = 0; k < 8; ++k) { S += sh[0][k][threadIdx.x]; S2 += sh[1][k][threadIdx.x]; }
    long long o = ((long long)(b * 32 + threadIdx.x) * nch + ch) * 2;
    part[o] = S; part[o + 1] = S2;
  }
}

__global__ __launch_bounds__(64) void gn_fin_kernel(const float* __restrict__ part,
    float* __restrict__ stats, int nch, int HW)
{
  const int bg = blockIdx.x;
  float s = 0.f, s2 = 0.f;
  for (int i = threadIdx.x; i < nch; i += 64) {
    long long o = ((long long)bg * nch + i) * 2;
    s += part[o]; s2 += part[o + 1];
  }
#pragma unroll
  for (int o = 32; o > 0; o >>= 1) { s += __shfl_down(s, o); s2 += __shfl_down(s2, o); }
  if (threadIdx.x == 0) {
    float inv = 1.f / (float)(HW * 8);
    float mean = s * inv;
    float var = s2 * inv - mean * mean;
    stats[bg * 2] = mean;
    stats[bg * 2 + 1] = rsqrtf(var + 1e-5f);
  }
}

// =====================================================================
// GN apply -> src fp32 + srcb bf16 + qb bf16 (src+pos)
// =====================================================================
__global__ void gn_apply_rm_kernel(const float* __restrict__ T, const float* __restrict__ stats,
    const float* __restrict__ gs, const float* __restrict__ gb,
    float* __restrict__ src, bhalf* __restrict__ srcb, bhalf* __restrict__ qb,
    const float* __restrict__ pos, int HW, int startRow)
{
  long long idx = (long long)blockIdx.x * 256 + threadIdx.x;
  int c = threadIdx.x & 255;
  long long row = idx >> 8;
  int b = (int)(row / HW);
  long long hw = row - (long long)b * HW;
  int g = c >> 3;
  float v = T[idx];
  v = (v - stats[(b * 32 + g) * 2]) * stats[(b * 32 + g) * 2 + 1] * gs[c] + gb[c];
  long long pr = (startRow + hw) * 256 + c;
  long long o = (long long)b * NLEN * 256 + pr;
  src[o] = v;
  srcb[o] = (bhalf)v;
  qb[o] = (bhalf)(v + pos[pr]);
}

// =====================================================================
// MSDeformAttn sampling: 8 ch/lane, 32 lanes/query, fused softmax
// (no max-shift: |logits| << 80, exp-safe). offaw bf16 [B*LEN][288].
// =====================================================================
__global__ __launch_bounds__(256) void deform_kernel(const bhalf* __restrict__ value,
    const bhalf* __restrict__ offaw, bhalf* __restrict__ out)
{
  const int t = threadIdx.x;
  const int q = t >> 5;
  const int sub = t & 31;
  const int bi = blockIdx.x * 8 + q;
  const int i = bi % NLEN;
  const int bbase = bi - i;
  const int c0 = sub * 8;
  const int head = sub >> 2;
  int loc, Wq;
  if (i < 576)       { Wq = 24; loc = i; }
  else if (i < 2880) { Wq = 48; loc = i - 576; }
  else               { Wq = 96; loc = i - 2880; }
  const float rx = ((loc % Wq) + 0.5f) / (float)Wq;
  const float ry = ((loc / Wq) + 0.5f) / (float)Wq;
  const bhalf* offp = offaw + (long long)bi * 288 + head * 24;
  const bhalf* awp  = offaw + (long long)bi * 288 + 192 + head * 12;
  float aw[12];
  float ssum = 0.f;
#pragma unroll
  for (int j = 0; j < 12; ++j) { aw[j] = __expf((float)awp[j]); ssum += aw[j]; }
  const float sinv = 1.f / ssum;
  float acc[8] = {};
  const int starts[3] = {0, 576, 2880};
  const int Ls[3] = {24, 48, 96};
#pragma unroll
  for (int l = 0; l < 3; ++l) {
    const int Wl = Ls[l];
    const float fW = (float)Wl;
    const bhalf* vb = value + (long long)(bbase + starts[l]) * 256 + c0;
#pragma unroll
    for (int p = 0; p < 4; ++p) {
      const float ox = (float)offp[l * 8 + p * 2], oy = (float)offp[l * 8 + p * 2 + 1];
      const float a = aw[l * 4 + p] * sinv;
      const float x = (rx + ox / fW) * fW - 0.5f;
      const float y = (ry + oy / fW) * fW - 0.5f;
      const float x0f = floorf(x), y0f = floorf(y);
      const float wx = x - x0f, wy = y - y0f;
      const int x0 = (int)x0f, y0 = (int)y0f;
      const int x1 = x0 + 1, y1 = y0 + 1;
      const bool xv0 = (x0 >= 0) & (x0 < Wl);
      const bool xv1 = (x1 >= 0) & (x1 < Wl);
      const bool yv0 = (y0 >= 0) & (y0 < Wl);
      const bool yv1 = (y1 >= 0) & (y1 < Wl);
      const int cx0 = min(max(x0, 0), Wl - 1), cx1 = min(max(x1, 0), Wl - 1);
      const int cy0 = min(max(y0, 0), Wl - 1), cy1 = min(max(y1, 0), Wl - 1);
      const float w00 = (xv0 && yv0) ? (1.f - wx) * (1.f - wy) * a : 0.f;
      const float w01 = (xv1 && yv0) ? wx * (1.f - wy) * a : 0.f;
      const float w10 = (xv0 && yv1) ? (1.f - wx) * wy * a : 0.f;
      const float w11 = (xv1 && yv1) ? wx * wy * a : 0.f;
      const bh8 g00 = *(const bh8*)(vb + (cy0 * Wl + cx0) * 256);
      const bh8 g01 = *(const bh8*)(vb + (cy0 * Wl + cx1) * 256);
      const bh8 g10 = *(const bh8*)(vb + (cy1 * Wl + cx0) * 256);
      const bh8 g11 = *(const bh8*)(vb + (cy1 * Wl + cx1) * 256);
#pragma unroll
      for (int e = 0; e < 8; ++e)
        acc[e] = fmaf(w00, (float)g00[e], fmaf(w01, (float)g01[e],
                 fmaf(w10, (float)g10[e], fmaf(w11, (float)g11[e], acc[e]))));
    }
  }
  bh8 o;
#pragma unroll
  for (int e = 0; e < 8; ++e) o[e] = (bhalf)acc[e];
  *(bh8*)(out + (long long)bi * 256 + c0) = o;
}

// =====================================================================
// All 3 output transposes in ONE launch: src rows -> out[b][c][hw].
// ranges (32x32 tiles x 8 x B): lvl0 288 | lvl1 1152 | lvl2 4608
// =====================================================================
__global__ void transpose_out_kernel(const float* __restrict__ src,
    float* __restrict__ out0, float* __restrict__ out1, float* __restrict__ out2)
{
  int blk = blockIdx.x;
  int lvl, HW, startRow;
  float* out;
  if (blk < 288)       { lvl = 0; HW = 576;  startRow = 0;    out = out0; }
  else if (blk < 1440) { lvl = 1; HW = 2304; startRow = 576;  out = out1; blk -= 288; }
  else                 { lvl = 2; HW = 9216; startRow = 2880; out = out2; blk -= 1440; }
  int nx = HW / 32;
  int bx = blk % nx; int r = blk / nx;
  int cy = r % 8; int b = r / 8;
  __shared__ float tile[32][33];
  int w0 = bx * 32, c0 = cy * 32;
#pragma unroll
  for (int j = 0; j < 4; ++j) {
    int wl = threadIdx.y + 8 * j;
    tile[wl][threadIdx.x] = src[((long long)b * NLEN + startRow + w0 + wl) * 256 + c0 + threadIdx.x];
  }
  __syncthreads();
#pragma unroll
  for (int j = 0; j < 4; ++j) {
    int cl = threadIdx.y + 8 * j;
    out[((long long)b * 256 + c0 + cl) * HW + w0 + threadIdx.x] = tile[threadIdx.x][cl];
  }
}

// =====================================================================
// latb = GN(lat) + upsample2x(src lvl2), zero-padded layout
// =====================================================================
__global__ void lat_finish_rm_kernel(const bhalf* __restrict__ lat, const float* __restrict__ stats,
    const float* __restrict__ gs, const float* __restrict__ gb,
    const float* __restrict__ src, bhalf* __restrict__ latb)
{
  long long idx = (long long)blockIdx.x * 256 + threadIdx.x;
  int c = threadIdx.x & 255;
  long long row = idx >> 8;
  int b = (int)(row / 36864);
  int p = (int)(row - (long long)b * 36864);
  int y = p / 192, x = p % 192;
  int g = c >> 3;
  float v = (float)lat[idx];
  v = (v - stats[(b * 32 + g) * 2]) * stats[(b * 32 + g) * 2 + 1] * gs[c] + gb[c];
  float ys = fmaxf(y * 0.5f - 0.25f, 0.f);
  float xs = fmaxf(x * 0.5f - 0.25f, 0.f);
  int y0 = (int)ys; float wy = ys - (float)y0; int y1 = min(y0 + 1, 95);
  int x0 = (int)xs; float wx = xs - (float)x0; int x1 = min(x0 + 1, 95);
  const float* sp = src + ((long long)b * NLEN + 2880) * 256 + c;
  float r0 = sp[(long long)(y0 * 96 + x0) * 256] * (1.f - wx) + sp[(long long)(y0 * 96 + x1) * 256] * wx;
  float r1 = sp[(long long)(y1 * 96 + x0) * 256] * (1.f - wx) + sp[(long long)(y1 * 96 + x1) * 256] * wx;
  latb[((long long)b * 37636 + (long long)(y + 1) * 194 + (x + 1)) * 256 + c]
      = (bhalf)(v + r0 * (1.f - wy) + r1 * wy);
}

// =====================================================================
// Final GN+ReLU+transpose: convC bf16 [b][hw][c] -> Y fp32 [b][c][hw]
// =====================================================================
__global__ void gn_relu_tr_kernel(const bhalf* __restrict__ convC, const float* __restrict__ stats,
    const float* __restrict__ gs, const float* __restrict__ gb, float* __restrict__ Y)
{
  __shared__ float tile[32][33];
  int b = blockIdx.z;
  int hw0 = blockIdx.x * 32, c0 = blockIdx.y * 32;
#pragma unroll
  for (int j = 0; j < 4; ++j) {
    int hwl = threadIdx.y + 8 * j;
    int c = c0 + threadIdx.x;
    int g = c >> 3;
    float v = (float)convC[((long long)b * 36864 + hw0 + hwl) * 256 + c];
    v = (v - stats[(b * 32 + g) * 2]) * stats[(b * 32 + g) * 2 + 1] * gs[c] + gb[c];
    tile[hwl][threadIdx.x] = fmaxf(v, 0.f);
  }
  __syncthreads();
#pragma unroll
  for (int j = 0; j < 4; ++j) {
    int cl = threadIdx.y + 8 * j;
    Y[((long long)b * 256 + c0 + cl) * 36864 + hw0 + threadIdx.x] = tile[threadIdx.x][cl];
  }
}

// =====================================================================
extern "C" void kernel_launch(void* const* d_in, const int* in_sizes, int n_in,
                              void* d_out, int out_size, void* d_ws, size_t ws_size,
                              hipStream_t stream)
{
  const float* res2 = (const float*)d_in[0];
  const float* res3 = (const float*)d_in[1];
  const float* res4 = (const float*)d_in[2];
  const float* res5 = (const float*)d_in[3];
  const float* pw[3]  = {(const float*)d_in[4],  (const float*)d_in[8],  (const float*)d_in[12]};
  const float* pb[3]  = {(const float*)d_in[5],  (const float*)d_in[9],  (const float*)d_in[13]};
  const float* gss[3] = {(const float*)d_in[6],  (const float*)d_in[10], (const float*)d_in[14]};
  const float* gbb[3] = {(const float*)d_in[7],  (const float*)d_in[11], (const float*)d_in[15]};
  const float* level_embed = (const float*)d_in[16];
  const float* off_w = (const float*)d_in[17];
  const float* off_b = (const float*)d_in[18];
  const float* aw_w  = (const float*)d_in[19];
  const float* aw_b  = (const float*)d_in[20];
  const float* val_w = (const float*)d_in[21];
  const float* val_b = (const float*)d_in[22];
  const float* out_w = (const float*)d_in[23];
  const float* out_b = (const float*)d_in[24];
  const float* ln1_s = (const float*)d_in[25];
  const float* ln1_b = (const float*)d_in[26];
  const float* ffn1_w = (const float*)d_in[27];
  const float* ffn1_b = (const float*)d_in[28];
  const float* ffn2_w = (const float*)d_in[29];
  const float* ffn2_b = (const float*)d_in[30];
  const float* ln2_s = (const float*)d_in[31];
  const float* ln2_b = (const float*)d_in[32];
  const float* lat_w = (const float*)d_in[33];
  const float* lat_gs = (const float*)d_in[34];
  const float* lat_gb = (const float*)d_in[35];
  const float* fpn_w = (const float*)d_in[36];
  const float* fpn_gs = (const float*)d_in[37];
  const float* fpn_gb = (const float*)d_in[38];

  char* W = (char*)d_ws;
  float* src   = (float*)(W + 0);
  float* pos   = (float*)(W + 24772608LL);
  float* tmp   = (float*)(W + 37158912LL);
  bhalf* srcb  = (bhalf*)(W + 61931520LL);
  bhalf* wreg  = (bhalf*)(W + 74317824LL);
  float* stats = (float*)(W + 86212608LL);
  float* part  = (float*)(W + 86213120LL);
  float* offaw_b = (float*)(W + 86278656LL);
  char*  U     = W + 86286848LL;

  bhalf* valT   = wreg + 0;
  bhalf* offawT = wreg + 393216;
  bhalf* outT   = wreg + 835584;
  bhalf* f1T    = wreg + 1228800;
  bhalf* f2T    = wreg + 2801664;
  bhalf* pwb5   = wreg + 4374528;
  bhalf* pwb4   = wreg + 4898816;
  bhalf* pwb3   = wreg + 5160960;
  bhalf* latwb  = wreg + 5292032;
  bhalf* fpnT   = wreg + 5357568;

  bhalf* qb      = (bhalf*)(U + 0);
  bhalf* valueb  = (bhalf*)(U + 12386304LL);
  bhalf* sampb   = (bhalf*)(U + 24772608LL);
  bhalf* offbuf  = (bhalf*)(U + 37158912LL);
  bhalf* hbuf    = (bhalf*)(U + 65028096LL);
  bhalf* featT   = (bhalf*)(U + 24772608LL);   // projection-phase only
  bhalf* res2T   = (bhalf*)(U + 0);
  bhalf* latbf   = (bhalf*)(U + 37748736LL);
  bhalf* latb    = (bhalf*)(U + 75497472LL);

  float* Yout = (float*)d_out;
  float* out0 = Yout + 18874368LL;
  float* out1 = Yout + 19169280LL;
  float* out2 = Yout + 20348928LL;

  const int M = BB * NLEN;  // 24192

  // ---- weight prep (2 launches) ----
  wprep_t_kernel<<<dim3(4272), dim3(32, 8), 0, stream>>>(
      val_w, off_w, aw_w, out_w, ffn1_w, ffn2_w,
      valT, offawT, offawT + 192 * 256, outT, f1T, f2T);
  wprep_m_kernel<<<dim3(6151), dim3(256), 0, stream>>>(
      fpn_w, fpnT, pw[0], pwb5, pw[1], pwb4, pw[2], pwb3,
      lat_w, latwb, off_b, aw_b, offaw_b);

  // ---- positional embedding ----
  pos_kernel<<<dim3(NLEN), dim3(256), 0, stream>>>(pos, level_embed);

  // ---- input projections + GN -> src/srcb/qb ----
  const float* feats[3] = {res5, res4, res3};
  const bhalf* pwbs[3] = {pwb5, pwb4, pwb3};
  const int cins[3] = {2048, 1024, 512};
  const int HWs[3] = {576, 2304, 9216};
  const int startsHost[3] = {0, 576, 2880};
  const int nchs[3] = {16, 64, 128};
  for (int lvl = 0; lvl < 3; ++lvl) {
    int HW = HWs[lvl], cin = cins[lvl], nch = nchs[lvl];
    tfeat_kernel<<<dim3(HW / 32, cin / 32, BB), dim3(32, 8), 0, stream>>>(feats[lvl], featT, cin, HW);
    bgemm_t_kernel<4><<<dim3(4, (HW + 127) / 128, BB), dim3(256), 0, stream>>>(
        featT, pwbs[lvl], pb[lvl], tmp, HW, 256, cin,
        (long long)HW * cin, 0LL, (long long)HW * 256, 0, 0);
    gn_part_kernel<<<dim3(nch, BB), dim3(256), 0, stream>>>(tmp, part, HW, 0, nch);
    gn_fin_kernel<<<dim3(64), dim3(64), 0, stream>>>(part, stats, nch, HW);
    gn_apply_rm_kernel<<<dim3(BB * HW), dim3(256), 0, stream>>>(
        tmp, stats, gss[lvl], gbb[lvl], src, srcb, qb, pos, HW, startsHost[lvl]);
  }

  // ---- 6 encoder layers ----
  for (int l = 0; l < 6; ++l) {
    bgemm_t_kernel<4><<<dim3(4, M / 128, 1), dim3(256), 0, stream>>>(
        srcb, valT + (long long)l * 65536, val_b + l * 256, valueb,
        M, 256, 256, 0LL, 0LL, 0LL, 1, 0);
    bgemm_t_kernel<6><<<dim3(3, M / 128, 1), dim3(256), 0, stream>>>(
        qb, offawT + (long long)l * 73728, offaw_b + l * 288, offbuf,
        M, 288, 256, 0LL, 0LL, 0LL, 1, 0);
    deform_kernel<<<dim3(M / 8), dim3(256), 0, stream>>>(valueb, offbuf, sampb);
    bgemm_ln_kernel<<<dim3(M / 32), dim3(256), 0, stream>>>(
        sampb, outT + (long long)l * 65536, out_b + l * 256,
        src, srcb, nullptr, pos, ln1_s + l * 256, ln1_b + l * 256, M, 256);
    bgemm_t_kernel<8><<<dim3(8, M / 128, 1), dim3(256), 0, stream>>>(
        srcb, f1T + (long long)l * 262144, ffn1_b + l * 1024, hbuf,
        M, 1024, 256, 0LL, 0LL, 0LL, 1, 1);
    bgemm_ln_kernel<<<dim3(M / 32), dim3(256), 0, stream>>>(
        hbuf, f2T + (long long)l * 262144, ffn2_b + l * 256,
        src, srcb, qb, pos, ln2_s + l * 256, ln2_b + l * 256, M, 1024);
  }

  // ---- output transposes (1 launch) ----
  transpose_out_kernel<<<dim3(6048), dim3(32, 8), 0, stream>>>(src, out0, out1, out2);

  // ---- FPN ----
  tfeat_kernel<<<dim3(1152, 8, BB), dim3(32, 8), 0, stream>>>(res2, res2T, 256, 36864);
  bgemm_t_kernel<4><<<dim3(4, 288, BB), dim3(256), 0, stream>>>(
      res2T, latwb, nullptr, latbf, 36864, 256, 256,
      36864LL * 256, 0LL, 36864LL * 256, 1, 0);
  gn_part_kernel<<<dim3(128, BB), dim3(256), 0, stream>>>(latbf, part, 36864, 1, 128);
  gn_fin_kernel<<<dim3(64), dim3(64), 0, stream>>>(part, stats, 128, 36864);
  border_zero_kernel<<<dim3((BB * 4 * 194 + 255) / 256), dim3(256), 0, stream>>>(latb);
  lat_finish_rm_kernel<<<dim3(73728), dim3(256), 0, stream>>>(latbf, stats, lat_gs, lat_gb, src, latb);
  bgemm_conv_kernel<<<dim3(2, 288, BB), dim3(256), 0, stream>>>(latb, fpnT, latbf);
  gn_part_kernel<<<dim3(128, BB), dim3(256), 0, stream>>>(latbf, part, 36864, 1, 128);
  gn_fin_kernel<<<dim3(64), dim3(64), 0, stream>>>(part, stats, 128, 36864);
  gn_relu_tr_kernel<<<dim3(1152, 8, BB), dim3(32, 8), 0, stream>>>(latbf, stats, fpn_gs, fpn_gb, Yout);
}

// Round 14
// 1531.070 us; speedup vs baseline: 1.2030x; 1.0332x over previous
//
#include <hip/hip_runtime.h>
#include <math.h>

#define NLEN 12096
#define BB 2

typedef __bf16 bhalf;
typedef bhalf bh8 __attribute__((ext_vector_type(8)));
typedef bhalf bh4 __attribute__((ext_vector_type(4)));
typedef float f32x4 __attribute__((ext_vector_type(4)));

// LDS 16B-slot swizzle (verified round 8: bank conflicts -> 0). BK=32.
__device__ __forceinline__ int swz(int row) { return (row >> 1) & 3; }

// Bijective XCD-chunk swizzle (T1, m204).
__device__ __forceinline__ int xcd_swz(int id, int nwg) {
  int q = nwg >> 3, r = nwg & 7;
  int xcd = id & 7, pos = id >> 3;
  int base = (xcd < r) ? xcd * (q + 1) : r * (q + 1) + (xcd - r) * q;
  return base + pos;
}

#define GLOAD_LDS16(g, l) \
  __builtin_amdgcn_global_load_lds( \
      (const __attribute__((address_space(1))) unsigned int*)(g), \
      (__attribute__((address_space(3))) unsigned int*)(l), 16, 0, 0)

// =====================================================================
// bf16 MFMA GEMM, tile 128 x (16*BNF), BK=32, 4 waves (2x2).
// =====================================================================
template<int BNF>
__global__ __launch_bounds__(256) void bgemm_t_kernel(
    const bhalf* __restrict__ A, const bhalf* __restrict__ Bt,
    const float* __restrict__ bias, void* __restrict__ Cout,
    int M, int N, int K, long long sA, long long sB, long long sC,
    int outBf16, int relu)
{
  constexpr int BN = BNF * 16;
  constexpr int ROWS = 128 + BN;
  constexpr int UNITS = ROWS * 4;
  constexpr int ITERS = (UNITS + 255) / 256;
  constexpr int NFR = BNF / 2;
  const int gx = gridDim.x, gy = gridDim.y;
  const int nwg = gx * gy * gridDim.z;
  int flat = (blockIdx.z * gy + blockIdx.y) * gx + blockIdx.x;
  int logical = xcd_swz(flat, nwg);
  const int bz = logical / (gx * gy);
  int rem = logical - bz * gx * gy;
  const int by = rem / gx;
  const int bx = rem - by * gx;

  A += bz * sA; Bt += bz * sB;
  const int m0 = by * 128, n0 = bx * BN;
  __shared__ __align__(16) bhalf Ls[ROWS * 32];
  const int t = threadIdx.x;
  const int lane = t & 63;
  const int w = t >> 6;
  const int wbase = t & 192;
  const int wm = (w >> 1) * 64, wn = (w & 1) * (BN / 2);
  const int fr = lane & 15, fg = lane >> 4;
  f32x4 acc[4][NFR] = {};
  for (int k0 = 0; k0 < K; k0 += 32) {
#pragma unroll
    for (int j = 0; j < ITERS; ++j) {
      int u = t + j * 256;
      if (UNITS % 256 == 0 || u < UNITS) {
        int row = u >> 2, up = u & 3;
        int kcg = ((up ^ swz(row)) * 8);
        const bhalf* gsrc;
        if (row < 128) {
          int m = m0 + row; m = (m < M) ? m : (M - 1);
          gsrc = A + (long long)m * K + k0 + kcg;
        } else {
          int n = n0 + row - 128; n = (n < N) ? n : (N - 1);
          gsrc = Bt + (long long)n * K + k0 + kcg;
        }
        GLOAD_LDS16(gsrc, Ls + (long long)(wbase + j * 256) * 8);
      }
    }
    __syncthreads();
    bh8 af[4], bf[NFR];
#pragma unroll
    for (int mi = 0; mi < 4; ++mi) {
      int r = wm + mi * 16 + fr;
      af[mi] = *(const bh8*)(Ls + r * 32 + ((fg ^ swz(r)) * 8));
    }
#pragma unroll
    for (int ni = 0; ni < NFR; ++ni) {
      int r = 128 + wn + ni * 16 + fr;
      bf[ni] = *(const bh8*)(Ls + r * 32 + ((fg ^ swz(r)) * 8));
    }
#pragma unroll
    for (int mi = 0; mi < 4; ++mi)
#pragma unroll
      for (int ni = 0; ni < NFR; ++ni)
        acc[mi][ni] = __builtin_amdgcn_mfma_f32_16x16x32_bf16(af[mi], bf[ni], acc[mi][ni], 0, 0, 0);
    __syncthreads();
  }
  float* Cf = (float*)Cout + bz * sC;
  bhalf* Cb = (bhalf*)Cout + bz * sC;
#pragma unroll
  for (int mi = 0; mi < 4; ++mi) {
#pragma unroll
    for (int r = 0; r < 4; ++r) {
      int m = m0 + wm + mi * 16 + fg * 4 + r;
      if (m >= M) continue;
#pragma unroll
      for (int ni = 0; ni < NFR; ++ni) {
        int n = n0 + wn + ni * 16 + fr;
        if (n >= N) continue;
        float v = acc[mi][ni][r];
        if (bias) v += bias[n];
        if (relu) v = fmaxf(v, 0.f);
        if (outBf16) Cb[(long long)m * N + n] = (bhalf)v;
        else         Cf[(long long)m * N + n] = v;
      }
    }
  }
}

// =====================================================================
// Fused GEMM + bias + residual(bf16) + LayerNorm. Tile 32x256, BK=32.
// Hidden state is bf16-only: y = LN(srcb + A@Bt^T + bias) -> srcb, qb.
// =====================================================================
__global__ __launch_bounds__(256) void bgemm_ln_kernel(
    const bhalf* __restrict__ A, const bhalf* __restrict__ Bt,
    const float* __restrict__ bias,
    bhalf* __restrict__ srcb, bhalf* __restrict__ qbOut,
    const float* __restrict__ pos,
    const float* __restrict__ ls, const float* __restrict__ lb,
    int M, int K)
{
  const int nwg = gridDim.x;
  const int bid = xcd_swz(blockIdx.x, nwg);
  const int m0 = bid * 32;
  __shared__ __align__(16) bhalf Ls[288 * 32];
  __shared__ float shS[32][2], shQ[32][2];
  const int t = threadIdx.x;
  const int lane = t & 63;
  const int w = t >> 6;
  const int wbase = t & 192;
  const int wm = (w >> 1) * 16, wn = (w & 1) * 128;
  const int fr = lane & 15, fg = lane >> 4;
  f32x4 acc[8] = {};
  for (int k0 = 0; k0 < K; k0 += 32) {
#pragma unroll
    for (int j = 0; j < 5; ++j) {
      int u = t + j * 256;
      if (u < 1152) {
        int row = u >> 2, up = u & 3;
        int kcg = ((up ^ swz(row)) * 8);
        const bhalf* gsrc = (row < 32)
            ? (A + (long long)(m0 + row) * K + k0 + kcg)
            : (Bt + (long long)(row - 32) * K + k0 + kcg);
        GLOAD_LDS16(gsrc, Ls + (long long)(wbase + j * 256) * 8);
      }
    }
    __syncthreads();
    bh8 af, bf[8];
    {
      int r = wm + fr;
      af = *(const bh8*)(Ls + r * 32 + ((fg ^ swz(r)) * 8));
    }
#pragma unroll
    for (int ni = 0; ni < 8; ++ni) {
      int r = 32 + wn + ni * 16 + fr;
      bf[ni] = *(const bh8*)(Ls + r * 32 + ((fg ^ swz(r)) * 8));
    }
#pragma unroll
    for (int ni = 0; ni < 8; ++ni)
      acc[ni] = __builtin_amdgcn_mfma_f32_16x16x32_bf16(af, bf[ni], acc[ni], 0, 0, 0);
    __syncthreads();
  }
  // epilogue: v = acc + bias + residual(bf16); per-row LN stats
#pragma unroll
  for (int r = 0; r < 4; ++r) {
    int rt = wm + fg * 4 + r;
    long long gm = m0 + rt;
    float s = 0.f, q = 0.f;
#pragma unroll
    for (int ni = 0; ni < 8; ++ni) {
      int col = wn + ni * 16 + fr;
      float v = acc[ni][r] + bias[col] + (float)srcb[gm * 256 + col];
      acc[ni][r] = v;
      s += v; q = fmaf(v, v, q);
    }
#pragma unroll
    for (int o = 1; o < 16; o <<= 1) { s += __shfl_xor(s, o); q += __shfl_xor(q, o); }
    if (fr == 0) { shS[rt][w & 1] = s; shQ[rt][w & 1] = q; }
  }
  __syncthreads();
#pragma unroll
  for (int r = 0; r < 4; ++r) {
    int rt = wm + fg * 4 + r;
    long long gm = m0 + rt;
    float S = shS[rt][0] + shS[rt][1];
    float Q = shQ[rt][0] + shQ[rt][1];
    float mean = S * (1.f / 256.f);
    float var = Q * (1.f / 256.f) - mean * mean;
    float rstd = rsqrtf(var + 1e-5f);
    int prow = (int)(gm % NLEN);
#pragma unroll
    for (int ni = 0; ni < 8; ++ni) {
      int col = wn + ni * 16 + fr;
      float y = (acc[ni][r] - mean) * rstd * ls[col] + lb[col];
      srcb[gm * 256 + col] = (bhalf)y;
      if (qbOut) qbOut[gm * 256 + col] = (bhalf)(y + pos[(long long)prow * 256 + col]);
    }
  }
}

// =====================================================================
// Implicit-GEMM 3x3 conv, BK=32, ci_block-major / tap-inner.
// =====================================================================
__global__ __launch_bounds__(256) void bgemm_conv_kernel(
    const bhalf* __restrict__ Ab, const bhalf* __restrict__ Bt,
    bhalf* __restrict__ Cout)
{
  const int gx = gridDim.x, gy = gridDim.y;
  const int nwg = gx * gy * gridDim.z;
  int flat = (blockIdx.z * gy + blockIdx.y) * gx + blockIdx.x;
  int logical = xcd_swz(flat, nwg);
  const int bz = logical / (gx * gy);
  int rem = logical - bz * gx * gy;
  const int by = rem / gx;
  const int bx = rem - by * gx;

  const bhalf* Apad = Ab + (long long)bz * 37636 * 256;
  const int m0 = by * 128, n0 = bx * 128;
  __shared__ __align__(16) bhalf As[128 * 32];
  __shared__ __align__(16) bhalf Bs[128 * 32];
  const int t = threadIdx.x;
  const int lane = t & 63;
  const int w = t >> 6;
  const int wbase = t & 192;
  const int wm = (w >> 1) * 64, wn = (w & 1) * 64;
  const int fr = lane & 15, fg = lane >> 4;
  int rowA[2], py[2], px[2], kcg[2];
#pragma unroll
  for (int j = 0; j < 2; ++j) {
    int id = t + j * 256;
    rowA[j] = id >> 2;
    kcg[j] = (((id & 3) ^ swz(rowA[j])) * 8);
    int m = m0 + rowA[j];
    py[j] = m / 192; px[j] = m % 192;
  }
  f32x4 acc[4][4] = {};
  for (int s = 0; s < 72; ++s) {
    const int cib = s / 9, tap = s % 9;
    const int ty = tap / 3, tx = tap % 3;
#pragma unroll
    for (int j = 0; j < 2; ++j) {
      GLOAD_LDS16(Apad + ((long long)(py[j] + ty) * 194 + px[j] + tx) * 256 + cib * 32 + kcg[j],
                  As + (wbase + j * 256) * 8);
      GLOAD_LDS16(Bt + (long long)(n0 + rowA[j]) * 2304 + s * 32 + kcg[j],
                  Bs + (wbase + j * 256) * 8);
    }
    __syncthreads();
    bh8 af[4], bf[4];
#pragma unroll
    for (int mi = 0; mi < 4; ++mi) {
      int r = wm + mi * 16 + fr;
      af[mi] = *(const bh8*)(As + r * 32 + ((fg ^ swz(r)) * 8));
    }
#pragma unroll
    for (int ni = 0; ni < 4; ++ni) {
      int r = wn + ni * 16 + fr;
      bf[ni] = *(const bh8*)(Bs + r * 32 + ((fg ^ swz(r)) * 8));
    }
#pragma unroll
    for (int mi = 0; mi < 4; ++mi)
#pragma unroll
      for (int ni = 0; ni < 4; ++ni)
        acc[mi][ni] = __builtin_amdgcn_mfma_f32_16x16x32_bf16(af[mi], bf[ni], acc[mi][ni], 0, 0, 0);
    __syncthreads();
  }
  bhalf* Cb = Cout + (long long)bz * 36864 * 256;
#pragma unroll
  for (int mi = 0; mi < 4; ++mi)
#pragma unroll
    for (int r = 0; r < 4; ++r) {
      int m = m0 + wm + mi * 16 + fg * 4 + r;
#pragma unroll
      for (int ni = 0; ni < 4; ++ni) {
        int n = n0 + wn + ni * 16 + fr;
        Cb[(long long)m * 256 + n] = (bhalf)acc[mi][ni][r];
      }
    }
}

// =====================================================================
// Fused weight transpose+convert (6 groups, one launch).
// =====================================================================
__global__ void wprep_t_kernel(
    const float* __restrict__ s0, const float* __restrict__ s1,
    const float* __restrict__ s2, const float* __restrict__ s3,
    const float* __restrict__ s4, const float* __restrict__ s5,
    bhalf* __restrict__ d0, bhalf* __restrict__ d1, bhalf* __restrict__ d2,
    bhalf* __restrict__ d3, bhalf* __restrict__ d4, bhalf* __restrict__ d5)
{
  const int KdA[6]  = {256, 256, 256, 256, 256, 1024};
  const int NdA[6]  = {256, 192, 96, 256, 1024, 256};
  const long long zdA[6] = {65536, 73728, 73728, 65536, 262144, 262144};
  const int cum[6]  = {384, 672, 816, 1200, 2736, 4272};
  int blk = blockIdx.x;
  int seg = 0;
#pragma unroll
  for (int i = 0; i < 6; ++i) if (blk >= cum[i]) seg = i + 1;
  int base = (seg == 0) ? 0 : cum[seg - 1];
  int idx = blk - base;
  const float* Wsrc = (seg == 0) ? s0 : (seg == 1) ? s1 : (seg == 2) ? s2
                    : (seg == 3) ? s3 : (seg == 4) ? s4 : s5;
  bhalf* out = (seg == 0) ? d0 : (seg == 1) ? d1 : (seg == 2) ? d2
             : (seg == 3) ? d3 : (seg == 4) ? d4 : d5;
  int Kd = KdA[seg], Nd = NdA[seg];
  int nx = Nd / 32, ny = Kd / 32;
  int z = idx / (nx * ny);
  int r = idx - z * nx * ny;
  int ky = r / nx, nxi = r - ky * nx;
  __shared__ float tile[32][33];
  long long zi = (long long)z * Kd * Nd;
  long long zo = (long long)z * zdA[seg];
  int n0 = nxi * 32, k0 = ky * 32;
#pragma unroll
  for (int j = 0; j < 4; ++j) {
    int kk = threadIdx.y + 8 * j;
    tile[kk][threadIdx.x] = Wsrc[zi + (long long)(k0 + kk) * Nd + n0 + threadIdx.x];
  }
  __syncthreads();
#pragma unroll
  for (int j = 0; j < 4; ++j) {
    int nn = threadIdx.y + 8 * j;
    out[zo + (long long)(n0 + nn) * Kd + k0 + threadIdx.x] = (bhalf)tile[threadIdx.x][nn];
  }
}

// =====================================================================
// Fused misc weight prep (fpnw + cvts + biascat).
// =====================================================================
__global__ void wprep_m_kernel(
    const float* __restrict__ fpn_w, bhalf* __restrict__ fpnT,
    const float* __restrict__ pw5, bhalf* __restrict__ pwb5,
    const float* __restrict__ pw4, bhalf* __restrict__ pwb4,
    const float* __restrict__ pw3, bhalf* __restrict__ pwb3,
    const float* __restrict__ lat_w, bhalf* __restrict__ latwb,
    const float* __restrict__ ob, const float* __restrict__ ab,
    float* __restrict__ offaw_b)
{
  int blk = blockIdx.x, t = threadIdx.x;
  if (blk < 2304) {
    int o = blk * 256 + t;
    int co = o / 2304, r = o % 2304;
    int cib = r / 288, rr = r % 288, tap = rr >> 5, cil = rr & 31;
    int ci = cib * 32 + cil;
    fpnT[o] = (bhalf)fpn_w[(co * 256 + ci) * 9 + tap];
  } else if (blk < 4352) {
    int i = (blk - 2304) * 256 + t; pwb5[i] = (bhalf)pw5[i];
  } else if (blk < 5376) {
    int i = (blk - 4352) * 256 + t; pwb4[i] = (bhalf)pw4[i];
  } else if (blk < 5888) {
    int i = (blk - 5376) * 256 + t; pwb3[i] = (bhalf)pw3[i];
  } else if (blk < 6144) {
    int i = (blk - 5888) * 256 + t; latwb[i] = (bhalf)lat_w[i];
  } else {
    int i = (blk - 6144) * 256 + t;
    if (i < 6 * 288) {
      int l = i / 288, c = i % 288;
      offaw_b[i] = (c < 192) ? ob[l * 192 + c] : ab[l * 96 + c - 192];
    }
  }
}

__global__ void tfeat_kernel(const float* __restrict__ Fsrc, bhalf* __restrict__ out,
                             int Ci, int HW)
{
  __shared__ float tile[32][33];
  long long zo = (long long)blockIdx.z * Ci * HW;
  int hw0 = blockIdx.x * 32, c0 = blockIdx.y * 32;
#pragma unroll
  for (int j = 0; j < 4; ++j) {
    int cc = threadIdx.y + 8 * j;
    tile[cc][threadIdx.x] = Fsrc[zo + (long long)(c0 + cc) * HW + hw0 + threadIdx.x];
  }
  __syncthreads();
#pragma unroll
  for (int j = 0; j < 4; ++j) {
    int hh = threadIdx.y + 8 * j;
    out[zo + (long long)(hw0 + hh) * Ci + c0 + threadIdx.x] = (bhalf)tile[threadIdx.x][hh];
  }
}

// zero 1-px border of padded [B][194*194][256] bf16 buffer
__global__ void border_zero_kernel(bhalf* __restrict__ latb)
{
  int idx = blockIdx.x * 256 + threadIdx.x;
  int total = BB * 4 * 194;
  if (idx >= total) return;
  int b = idx / (4 * 194);
  int r = idx - b * 4 * 194;
  int strip = r / 194, p = r % 194;
  int y, x;
  if (strip == 0)      { y = 0;   x = p; }
  else if (strip == 1) { y = 193; x = p; }
  else if (strip == 2) { y = p;   x = 0; }
  else                 { y = p;   x = 193; }
  uint4* dst = (uint4*)(latb + ((long long)b * 37636 + (long long)y * 194 + x) * 256);
#pragma unroll
  for (int j = 0; j < 32; ++j) dst[j] = make_uint4(0u, 0u, 0u, 0u);
}

// =====================================================================
// Sine positional embedding + level embed
// =====================================================================
__global__ void pos_kernel(float* __restrict__ pos, const float* __restrict__ level_embed)
{
  int i = blockIdx.x, c = threadIdx.x;
  int lvl, Wq, loc;
  if (i < 576)       { lvl = 0; Wq = 24; loc = i; }
  else if (i < 2880) { lvl = 1; Wq = 48; loc = i - 576; }
  else               { lvl = 2; Wq = 96; loc = i - 2880; }
  int h = loc / Wq, wcol = loc % Wq;
  int cc = c & 127;
  float coord = (c < 128) ? (float)(h + 1) : (float)(wcol + 1);
  float denom = (float)Wq + 1e-6f;
  float v = coord / denom * 6.28318530717958647692f;
  float tp = powf(10000.0f, (float)(cc & ~1) * (1.0f / 128.0f));
  float ang = v / tp;
  float val = (cc & 1) ? cosf(ang) : sinf(ang);
  pos[(long long)i * 256 + c] = val + level_embed[lvl * 256 + c];
}

// =====================================================================
// GN stats, two-pass, coalesced. X row-major [B][HW][256] (bf16 or f32).
// =====================================================================
__global__ __launch_bounds__(256) void gn_part_kernel(const void* __restrict__ X,
    float* __restrict__ part, int HW, int isBf16, int nch)
{
  const int b = blockIdx.y, ch = blockIdx.x;
  const int rows = (HW + nch - 1) / nch;
  const int r0 = ch * rows;
  const int r1 = min(r0 + rows, HW);
  const int cg = threadIdx.x & 31;
  const int ro = threadIdx.x >> 5;
  float s = 0.f, s2 = 0.f;
  if (isBf16) {
    const bhalf* p = (const bhalf*)X + (long long)b * HW * 256 + cg * 8;
    for (int r = r0 + ro; r < r1; r += 8) {
      bh8 v = *(const bh8*)(p + (long long)r * 256);
#pragma unroll
      for (int j = 0; j < 8; ++j) { float f = (float)v[j]; s += f; s2 = fmaf(f, f, s2); }
    }
  } else {
    const float* p = (const float*)X + (long long)b * HW * 256 + cg * 8;
    for (int r = r0 + ro; r < r1; r += 8) {
      f32x4 v0 = *(const f32x4*)(p + (long long)r * 256);
      f32x4 v1 = *(const f32x4*)(p + (long long)r * 256 + 4);
#pragma unroll
      for (int j = 0; j < 4; ++j) { s += v0[j]; s2 = fmaf(v0[j], v0[j], s2); }
#pragma unroll
      for (int j = 0; j < 4; ++j) { s += v1[j]; s2 = fmaf(v1[j], v1[j], s2); }
    }
  }
  __shared__ float sh[2][8][32];
  sh[0][ro][cg] = s; sh[1][ro][cg] = s2;
  __syncthreads();
  if (threadIdx.x < 32) {
    float S = 0.f, S2 = 0.f;
#pragma unroll
    for (int k = 0; k < 8; ++k) { S += sh[0][k][threadIdx.x]; S2 += sh[1][k][threadIdx.x]; }
    long long o = ((long long)(b * 32 + threadIdx.x) * nch + ch) * 2;
    part[o] = S; part[o + 1] = S2;
  }
}

__global__ __launch_bounds__(64) void gn_fin_kernel(const float* __restrict__ part,
    float* __restrict__ stats, int nch, int HW)
{
  const int bg = blockIdx.x;
  float s = 0.f, s2 = 0.f;
  for (int i = threadIdx.x; i < nch; i += 64) {
    long long o = ((long long)bg * nch + i) * 2;
    s += part[o]; s2 += part[o + 1];
  }
#pragma unroll
  for (int o = 32; o > 0; o >>= 1) { s += __shfl_down(s, o); s2 += __shfl_down(s2, o); }
  if (threadIdx.x == 0) {
    float inv = 1.f / (float)(HW * 8);
    float mean = s * inv;
    float var = s2 * inv - mean * mean;
    stats[bg * 2] = mean;
    stats[bg * 2 + 1] = rsqrtf(var + 1e-5f);
  }
}

// =====================================================================
// GN apply on bf16 proj output -> srcb bf16 + qb bf16 (v+pos)
// =====================================================================
__global__ void gn_apply_rm_kernel(const bhalf* __restrict__ T, const float* __restrict__ stats,
    const float* __restrict__ gs, const float* __restrict__ gb,
    bhalf* __restrict__ srcb, bhalf* __restrict__ qb,
    const float* __restrict__ pos, int HW, int startRow)
{
  long long idx = (long long)blockIdx.x * 256 + threadIdx.x;
  int c = threadIdx.x & 255;
  long long row = idx >> 8;
  int b = (int)(row / HW);
  long long hw = row - (long long)b * HW;
  int g = c >> 3;
  float v = (float)T[idx];
  v = (v - stats[(b * 32 + g) * 2]) * stats[(b * 32 + g) * 2 + 1] * gs[c] + gb[c];
  long long pr = (startRow + hw) * 256 + c;
  long long o = (long long)b * NLEN * 256 + pr;
  srcb[o] = (bhalf)v;
  qb[o] = (bhalf)(v + pos[pr]);
}

// =====================================================================
// MSDeformAttn sampling: 8 ch/lane, 32 lanes/query, fused softmax.
// =====================================================================
__global__ __launch_bounds__(256) void deform_kernel(const bhalf* __restrict__ value,
    const bhalf* __restrict__ offaw, bhalf* __restrict__ out)
{
  const int t = threadIdx.x;
  const int q = t >> 5;
  const int sub = t & 31;
  const int bi = blockIdx.x * 8 + q;
  const int i = bi % NLEN;
  const int bbase = bi - i;
  const int c0 = sub * 8;
  const int head = sub >> 2;
  int loc, Wq;
  if (i < 576)       { Wq = 24; loc = i; }
  else if (i < 2880) { Wq = 48; loc = i - 576; }
  else               { Wq = 96; loc = i - 2880; }
  const float rx = ((loc % Wq) + 0.5f) / (float)Wq;
  const float ry = ((loc / Wq) + 0.5f) / (float)Wq;
  const bhalf* offp = offaw + (long long)bi * 288 + head * 24;
  const bhalf* awp  = offaw + (long long)bi * 288 + 192 + head * 12;
  float aw[12];
  float ssum = 0.f;
#pragma unroll
  for (int j = 0; j < 12; ++j) { aw[j] = __expf((float)awp[j]); ssum += aw[j]; }
  const float sinv = 1.f / ssum;
  float acc[8] = {};
  const int starts[3] = {0, 576, 2880};
  const int Ls[3] = {24, 48, 96};
#pragma unroll
  for (int l = 0; l < 3; ++l) {
    const int Wl = Ls[l];
    const float fW = (float)Wl;
    const bhalf* vb = value + (long long)(bbase + starts[l]) * 256 + c0;
#pragma unroll
    for (int p = 0; p < 4; ++p) {
      const float ox = (float)offp[l * 8 + p * 2], oy = (float)offp[l * 8 + p * 2 + 1];
      const float a = aw[l * 4 + p] * sinv;
      const float x = (rx + ox / fW) * fW - 0.5f;
      const float y = (ry + oy / fW) * fW - 0.5f;
      const float x0f = floorf(x), y0f = floorf(y);
      const float wx = x - x0f, wy = y - y0f;
      const int x0 = (int)x0f, y0 = (int)y0f;
      const int x1 = x0 + 1, y1 = y0 + 1;
      const bool xv0 = (x0 >= 0) & (x0 < Wl);
      const bool xv1 = (x1 >= 0) & (x1 < Wl);
      const bool yv0 = (y0 >= 0) & (y0 < Wl);
      const bool yv1 = (y1 >= 0) & (y1 < Wl);
      const int cx0 = min(max(x0, 0), Wl - 1), cx1 = min(max(x1, 0), Wl - 1);
      const int cy0 = min(max(y0, 0), Wl - 1), cy1 = min(max(y1, 0), Wl - 1);
      const float w00 = (xv0 && yv0) ? (1.f - wx) * (1.f - wy) * a : 0.f;
      const float w01 = (xv1 && yv0) ? wx * (1.f - wy) * a : 0.f;
      const float w10 = (xv0 && yv1) ? (1.f - wx) * wy * a : 0.f;
      const float w11 = (xv1 && yv1) ? wx * wy * a : 0.f;
      const bh8 g00 = *(const bh8*)(vb + (cy0 * Wl + cx0) * 256);
      const bh8 g01 = *(const bh8*)(vb + (cy0 * Wl + cx1) * 256);
      const bh8 g10 = *(const bh8*)(vb + (cy1 * Wl + cx0) * 256);
      const bh8 g11 = *(const bh8*)(vb + (cy1 * Wl + cx1) * 256);
#pragma unroll
      for (int e = 0; e < 8; ++e)
        acc[e] = fmaf(w00, (float)g00[e], fmaf(w01, (float)g01[e],
                 fmaf(w10, (float)g10[e], fmaf(w11, (float)g11[e], acc[e]))));
    }
  }
  bh8 o;
#pragma unroll
  for (int e = 0; e < 8; ++e) o[e] = (bhalf)acc[e];
  *(bh8*)(out + (long long)bi * 256 + c0) = o;
}

// =====================================================================
// All 3 output transposes in ONE launch: srcb(bf16) -> out[b][c][hw] f32.
// =====================================================================
__global__ void transpose_out_kernel(const bhalf* __restrict__ srcb,
    float* __restrict__ out0, float* __restrict__ out1, float* __restrict__ out2)
{
  int blk = blockIdx.x;
  int HW, startRow;
  float* out;
  if (blk < 288)       { HW = 576;  startRow = 0;    out = out0; }
  else if (blk < 1440) { HW = 2304; startRow = 576;  out = out1; blk -= 288; }
  else                 { HW = 9216; startRow = 2880; out = out2; blk -= 1440; }
  int nx = HW / 32;
  int bx = blk % nx; int r = blk / nx;
  int cy = r % 8; int b = r / 8;
  __shared__ float tile[32][33];
  int w0 = bx * 32, c0 = cy * 32;
#pragma unroll
  for (int j = 0; j < 4; ++j) {
    int wl = threadIdx.y + 8 * j;
    tile[wl][threadIdx.x] =
        (float)srcb[((long long)b * NLEN + startRow + w0 + wl) * 256 + c0 + threadIdx.x];
  }
  __syncthreads();
#pragma unroll
  for (int j = 0; j < 4; ++j) {
    int cl = threadIdx.y + 8 * j;
    out[((long long)b * 256 + c0 + cl) * HW + w0 + threadIdx.x] = tile[threadIdx.x][cl];
  }
}

// =====================================================================
// latb = GN(lat) + upsample2x(srcb lvl2 bf16), zero-padded layout
// =====================================================================
__global__ void lat_finish_rm_kernel(const bhalf* __restrict__ lat, const float* __restrict__ stats,
    const float* __restrict__ gs, const float* __restrict__ gb,
    const bhalf* __restrict__ srcb, bhalf* __restrict__ latb)
{
  long long idx = (long long)blockIdx.x * 256 + threadIdx.x;
  int c = threadIdx.x & 255;
  long long row = idx >> 8;
  int b = (int)(row / 36864);
  int p = (int)(row - (long long)b * 36864);
  int y = p / 192, x = p % 192;
  int g = c >> 3;
  float v = (float)lat[idx];
  v = (v - stats[(b * 32 + g) * 2]) * stats[(b * 32 + g) * 2 + 1] * gs[c] + gb[c];
  float ys = fmaxf(y * 0.5f - 0.25f, 0.f);
  float xs = fmaxf(x * 0.5f - 0.25f, 0.f);
  int y0 = (int)ys; float wy = ys - (float)y0; int y1 = min(y0 + 1, 95);
  int x0 = (int)xs; float wx = xs - (float)x0; int x1 = min(x0 + 1, 95);
  const bhalf* sp = srcb + ((long long)b * NLEN + 2880) * 256 + c;
  float r0 = (float)sp[(long long)(y0 * 96 + x0) * 256] * (1.f - wx)
           + (float)sp[(long long)(y0 * 96 + x1) * 256] * wx;
  float r1 = (float)sp[(long long)(y1 * 96 + x0) * 256] * (1.f - wx)
           + (float)sp[(long long)(y1 * 96 + x1) * 256] * wx;
  latb[((long long)b * 37636 + (long long)(y + 1) * 194 + (x + 1)) * 256 + c]
      = (bhalf)(v + r0 * (1.f - wy) + r1 * wy);
}

// =====================================================================
// Final GN+ReLU+transpose: convC bf16 [b][hw][c] -> Y fp32 [b][c][hw]
// =====================================================================
__global__ void gn_relu_tr_kernel(const bhalf* __restrict__ convC, const float* __restrict__ stats,
    const float* __restrict__ gs, const float* __restrict__ gb, float* __restrict__ Y)
{
  __shared__ float tile[32][33];
  int b = blockIdx.z;
  int hw0 = blockIdx.x * 32, c0 = blockIdx.y * 32;
#pragma unroll
  for (int j = 0; j < 4; ++j) {
    int hwl = threadIdx.y + 8 * j;
    int c = c0 + threadIdx.x;
    int g = c >> 3;
    float v = (float)convC[((long long)b * 36864 + hw0 + hwl) * 256 + c];
    v = (v - stats[(b * 32 + g) * 2]) * stats[(b * 32 + g) * 2 + 1] * gs[c] + gb[c];
    tile[hwl][threadIdx.x] = fmaxf(v, 0.f);
  }
  __syncthreads();
#pragma unroll
  for (int j = 0; j < 4; ++j) {
    int cl = threadIdx.y + 8 * j;
    Y[((long long)b * 256 + c0 + cl) * 36864 + hw0 + threadIdx.x] = tile[threadIdx.x][cl];
  }
}

// =====================================================================
extern "C" void kernel_launch(void* const* d_in, const int* in_sizes, int n_in,
                              void* d_out, int out_size, void* d_ws, size_t ws_size,
                              hipStream_t stream)
{
  const float* res2 = (const float*)d_in[0];
  const float* res3 = (const float*)d_in[1];
  const float* res4 = (const float*)d_in[2];
  const float* res5 = (const float*)d_in[3];
  const float* pw[3]  = {(const float*)d_in[4],  (const float*)d_in[8],  (const float*)d_in[12]};
  const float* pb[3]  = {(const float*)d_in[5],  (const float*)d_in[9],  (const float*)d_in[13]};
  const float* gss[3] = {(const float*)d_in[6],  (const float*)d_in[10], (const float*)d_in[14]};
  const float* gbb[3] = {(const float*)d_in[7],  (const float*)d_in[11], (const float*)d_in[15]};
  const float* level_embed = (const float*)d_in[16];
  const float* off_w = (const float*)d_in[17];
  const float* off_b = (const float*)d_in[18];
  const float* aw_w  = (const float*)d_in[19];
  const float* aw_b  = (const float*)d_in[20];
  const float* val_w = (const float*)d_in[21];
  const float* val_b = (const float*)d_in[22];
  const float* out_w = (const float*)d_in[23];
  const float* out_b = (const float*)d_in[24];
  const float* ln1_s = (const float*)d_in[25];
  const float* ln1_b = (const float*)d_in[26];
  const float* ffn1_w = (const float*)d_in[27];
  const float* ffn1_b = (const float*)d_in[28];
  const float* ffn2_w = (const float*)d_in[29];
  const float* ffn2_b = (const float*)d_in[30];
  const float* ln2_s = (const float*)d_in[31];
  const float* ln2_b = (const float*)d_in[32];
  const float* lat_w = (const float*)d_in[33];
  const float* lat_gs = (const float*)d_in[34];
  const float* lat_gb = (const float*)d_in[35];
  const float* fpn_w = (const float*)d_in[36];
  const float* fpn_gs = (const float*)d_in[37];
  const float* fpn_gb = (const float*)d_in[38];

  char* W = (char*)d_ws;
  float* pos   = (float*)(W + 24772608LL);
  bhalf* tmpb  = (bhalf*)(W + 37158912LL);     // proj output bf16
  bhalf* srcb  = (bhalf*)(W + 61931520LL);     // canonical hidden state
  bhalf* wreg  = (bhalf*)(W + 74317824LL);
  float* stats = (float*)(W + 86212608LL);
  float* part  = (float*)(W + 86213120LL);
  float* offaw_b = (float*)(W + 86278656LL);
  char*  U     = W + 86286848LL;

  bhalf* valT   = wreg + 0;
  bhalf* offawT = wreg + 393216;
  bhalf* outT   = wreg + 835584;
  bhalf* f1T    = wreg + 1228800;
  bhalf* f2T    = wreg + 2801664;
  bhalf* pwb5   = wreg + 4374528;
  bhalf* pwb4   = wreg + 4898816;
  bhalf* pwb3   = wreg + 5160960;
  bhalf* latwb  = wreg + 5292032;
  bhalf* fpnT   = wreg + 5357568;

  bhalf* qb      = (bhalf*)(U + 0);
  bhalf* valueb  = (bhalf*)(U + 12386304LL);
  bhalf* sampb   = (bhalf*)(U + 24772608LL);
  bhalf* offbuf  = (bhalf*)(U + 37158912LL);
  bhalf* hbuf    = (bhalf*)(U + 65028096LL);
  bhalf* featT   = (bhalf*)(U + 24772608LL);   // projection-phase only
  bhalf* res2T   = (bhalf*)(U + 0);
  bhalf* latbf   = (bhalf*)(U + 37748736LL);
  bhalf* latb    = (bhalf*)(U + 75497472LL);

  float* Yout = (float*)d_out;
  float* out0 = Yout + 18874368LL;
  float* out1 = Yout + 19169280LL;
  float* out2 = Yout + 20348928LL;

  const int M = BB * NLEN;  // 24192

  // ---- weight prep (2 launches) ----
  wprep_t_kernel<<<dim3(4272), dim3(32, 8), 0, stream>>>(
      val_w, off_w, aw_w, out_w, ffn1_w, ffn2_w,
      valT, offawT, offawT + 192 * 256, outT, f1T, f2T);
  wprep_m_kernel<<<dim3(6151), dim3(256), 0, stream>>>(
      fpn_w, fpnT, pw[0], pwb5, pw[1], pwb4, pw[2], pwb3,
      lat_w, latwb, off_b, aw_b, offaw_b);

  // ---- positional embedding ----
  pos_kernel<<<dim3(NLEN), dim3(256), 0, stream>>>(pos, level_embed);

  // ---- input projections + GN -> srcb/qb ----
  const float* feats[3] = {res5, res4, res3};
  const bhalf* pwbs[3] = {pwb5, pwb4, pwb3};
  const int cins[3] = {2048, 1024, 512};
  const int HWs[3] = {576, 2304, 9216};
  const int startsHost[3] = {0, 576, 2880};
  const int nchs[3] = {16, 64, 128};
  for (int lvl = 0; lvl < 3; ++lvl) {
    int HW = HWs[lvl], cin = cins[lvl], nch = nchs[lvl];
    tfeat_kernel<<<dim3(HW / 32, cin / 32, BB), dim3(32, 8), 0, stream>>>(feats[lvl], featT, cin, HW);
    bgemm_t_kernel<4><<<dim3(4, (HW + 127) / 128, BB), dim3(256), 0, stream>>>(
        featT, pwbs[lvl], pb[lvl], tmpb, HW, 256, cin,
        (long long)HW * cin, 0LL, (long long)HW * 256, 1, 0);
    gn_part_kernel<<<dim3(nch, BB), dim3(256), 0, stream>>>(tmpb, part, HW, 1, nch);
    gn_fin_kernel<<<dim3(64), dim3(64), 0, stream>>>(part, stats, nch, HW);
    gn_apply_rm_kernel<<<dim3(BB * HW), dim3(256), 0, stream>>>(
        tmpb, stats, gss[lvl], gbb[lvl], srcb, qb, pos, HW, startsHost[lvl]);
  }

  // ---- 6 encoder layers ----
  for (int l = 0; l < 6; ++l) {
    bgemm_t_kernel<4><<<dim3(4, M / 128, 1), dim3(256), 0, stream>>>(
        srcb, valT + (long long)l * 65536, val_b + l * 256, valueb,
        M, 256, 256, 0LL, 0LL, 0LL, 1, 0);
    bgemm_t_kernel<6><<<dim3(3, M / 128, 1), dim3(256), 0, stream>>>(
        qb, offawT + (long long)l * 73728, offaw_b + l * 288, offbuf,
        M, 288, 256, 0LL, 0LL, 0LL, 1, 0);
    deform_kernel<<<dim3(M / 8), dim3(256), 0, stream>>>(valueb, offbuf, sampb);
    bgemm_ln_kernel<<<dim3(M / 32), dim3(256), 0, stream>>>(
        sampb, outT + (long long)l * 65536, out_b + l * 256,
        srcb, nullptr, pos, ln1_s + l * 256, ln1_b + l * 256, M, 256);
    bgemm_t_kernel<8><<<dim3(8, M / 128, 1), dim3(256), 0, stream>>>(
        srcb, f1T + (long long)l * 262144, ffn1_b + l * 1024, hbuf,
        M, 1024, 256, 0LL, 0LL, 0LL, 1, 1);
    bgemm_ln_kernel<<<dim3(M / 32), dim3(256), 0, stream>>>(
        hbuf, f2T + (long long)l * 262144, ffn2_b + l * 256,
        srcb, qb, pos, ln2_s + l * 256, ln2_b + l * 256, M, 1024);
  }

  // ---- output transposes (1 launch) ----
  transpose_out_kernel<<<dim3(6048), dim3(32, 8), 0, stream>>>(srcb, out0, out1, out2);

  // ---- FPN ----
  tfeat_kernel<<<dim3(1152, 8, BB), dim3(32, 8), 0, stream>>>(res2, res2T, 256, 36864);
  bgemm_t_kernel<4><<<dim3(4, 288, BB), dim3(256), 0, stream>>>(
      res2T, latwb, nullptr, latbf, 36864, 256, 256,
      36864LL * 256, 0LL, 36864LL * 256, 1, 0);
  gn_part_kernel<<<dim3(128, BB), dim3(256), 0, stream>>>(latbf, part, 36864, 1, 128);
  gn_fin_kernel<<<dim3(64), dim3(64), 0, stream>>>(part, stats, 128, 36864);
  border_zero_kernel<<<dim3((BB * 4 * 194 + 255) / 256), dim3(256), 0, stream>>>(latb);
  lat_finish_rm_kernel<<<dim3(73728), dim3(256), 0, stream>>>(latbf, stats, lat_gs, lat_gb, srcb, latb);
  bgemm_conv_kernel<<<dim3(2, 288, BB), dim3(256), 0, stream>>>(latb, fpnT, latbf);
  gn_part_kernel<<<dim3(128, BB), dim3(256), 0, stream>>>(latbf, part, 36864, 1, 128);
  gn_fin_kernel<<<dim3(64), dim3(64), 0, stream>>>(part, stats, 128, 36864);
  gn_relu_tr_kernel<<<dim3(1152, 8, BB), dim3(32, 8), 0, stream>>>(latbf, stats, fpn_gs, fpn_gb, Yout);
}